// Round 1
// baseline (267.439 us; speedup 1.0000x reference)
//
#include <hip/hip_runtime.h>
#include <math.h>

typedef unsigned short u16;
typedef unsigned int u32;
typedef __attribute__((ext_vector_type(8))) short bf16x8;
typedef __attribute__((ext_vector_type(4))) float f32x4;

// B=64, L=256, DIN=768, H=64, E=8, K=2, S=16; BL=16384. All inputs f32, output f32.

__device__ __forceinline__ float bf2f(u16 u) {
    union { u32 i; float f; } x; x.i = ((u32)u) << 16; return x.f;
}
__device__ __forceinline__ u16 f2bf(float f) {
    union { float f; u32 i; } x; x.f = f;
    u32 i = x.i;
    return (u16)((i + 0x7fffu + ((i >> 16) & 1u)) >> 16);
}
__device__ __forceinline__ u32 pack2(float a, float b) {
    return (u32)f2bf(a) | ((u32)f2bf(b) << 16);
}
__device__ __forceinline__ float wsum(float v) {
    #pragma unroll
    for (int o = 1; o < 64; o <<= 1) v += __shfl_xor(v, o, 64);
    return v;
}
__device__ __forceinline__ float gelu_f(float x) {
    return 0.5f * x * (1.0f + erff(x * 0.70710678118654752440f));
}

// ---------- 1a. partial gating ----------
__global__ __launch_bounds__(256) void k_gate_part(const float* __restrict__ dte,
                                                   const float* __restrict__ w_gate,
                                                   float* __restrict__ partial) {
    __shared__ float dmeanS[64];
    int p = blockIdx.x, tid = threadIdx.x, w = tid >> 6, lane = tid & 63;
    for (int i = 0; i < 16; i++) {
        int l = w * 16 + i;
        const float* pr = dte + ((size_t)p * 64 + l) * 768;
        float s = 0.f;
        #pragma unroll
        for (int j = 0; j < 3; j++) {
            float4 v = *(const float4*)(pr + (lane + j * 64) * 4);
            s += v.x + v.y + v.z + v.w;
        }
        s = wsum(s);
        if (lane == 0) dmeanS[l] = s * (1.f / 768.f);
    }
    __syncthreads();
    if (w == 0) {
        float dm = dmeanS[lane];
        int wl = (p & 3) * 64 + lane;
        #pragma unroll
        for (int e = 0; e < 8; e++) {
            float s = wsum(dm * w_gate[wl * 8 + e]);
            if (lane == 0) partial[p * 8 + e] = s;
        }
    }
}

// ---------- 1b. finalize gates + loss ----------
__global__ __launch_bounds__(256) void k_gate_fin(const float* __restrict__ partial,
                                                  const float* __restrict__ b_exp,
                                                  int* __restrict__ topi,
                                                  float* __restrict__ topg,
                                                  float* __restrict__ bias_y,
                                                  float* __restrict__ loss_out) {
    __shared__ float gS[64 * 8];
    __shared__ int i0S[64], i1S[64];
    __shared__ float g0S[64], g1S[64];
    int tid = threadIdx.x;
    if (tid < 64) {
        float lg[8];
        #pragma unroll
        for (int e = 0; e < 8; e++)
            lg[e] = partial[(tid * 4 + 0) * 8 + e] + partial[(tid * 4 + 1) * 8 + e] +
                    partial[(tid * 4 + 2) * 8 + e] + partial[(tid * 4 + 3) * 8 + e];
        int i0 = 0; float v0 = lg[0];
        #pragma unroll
        for (int e = 1; e < 8; e++) if (lg[e] > v0) { v0 = lg[e]; i0 = e; }
        int i1 = -1; float v1 = -1e30f;
        #pragma unroll
        for (int e = 0; e < 8; e++) if (e != i0 && lg[e] > v1) { v1 = lg[e]; i1 = e; }
        if (i1 < 0) i1 = (i0 + 1) & 7;
        float e2 = expf(v1 - v0);
        float g0 = 1.f / (1.f + e2);
        float g1 = e2 / (1.f + e2);
        #pragma unroll
        for (int e = 0; e < 8; e++) gS[tid * 8 + e] = 0.f;
        gS[tid * 8 + i0] = g0;
        gS[tid * 8 + i1] = g1;
        i0S[tid] = i0; i1S[tid] = i1; g0S[tid] = g0; g1S[tid] = g1;
        topi[tid * 2] = i0; topi[tid * 2 + 1] = i1;
        topg[tid * 2] = g0; topg[tid * 2 + 1] = g1;
    }
    __syncthreads();
    for (int idx = tid; idx < 4096; idx += 256) {
        int b = idx >> 6, h = idx & 63;
        bias_y[idx] = g0S[b] * b_exp[i0S[b] * 64 + h] + g1S[b] * b_exp[i1S[b] * 64 + h];
    }
    if (tid < 64) {
        float g[8];
        #pragma unroll
        for (int e = 0; e < 8; e++) g[e] = gS[tid * 8 + e];
        float imp[8], ld[8];
        #pragma unroll
        for (int e = 0; e < 8; e++) {
            imp[e] = wsum(g[e]);
            ld[e]  = wsum(g[e] > 0.f ? 1.f : 0.f);
        }
        if (tid == 0) {
            float l = 0.f;
            {
                float s = 0.f;
                #pragma unroll
                for (int e = 0; e < 8; e++) s += imp[e];
                float mn = s / 8.f, v = 0.f;
                #pragma unroll
                for (int e = 0; e < 8; e++) { float d = imp[e] - mn; v += d * d; }
                l += (v / 7.f) / (mn * mn + 1e-10f);
            }
            {
                float s = 0.f;
                #pragma unroll
                for (int e = 0; e < 8; e++) s += ld[e];
                float mn = s / 8.f, v = 0.f;
                #pragma unroll
                for (int e = 0; e < 8; e++) { float d = ld[e] - mn; v += d * d; }
                l += (v / 7.f) / (mn * mn + 1e-10f);
            }
            loss_out[0] = 0.01f * l;
        }
    }
}

// ---------- 2. MFMA GEMMs, BK=64, conflict-free staging, register prefetch.
//   bid<512: pair=(bid>>1) rows, kind=bid&1 (0=sh f32, 1=y bf16);
//   bid>=512: kind2 rgb -> out plane. ----------
__global__ __launch_bounds__(256) void k_gemm3(const float* __restrict__ dte,
                                               const float* __restrict__ x,
                                               const float* __restrict__ W_sh,
                                               const float* __restrict__ b_sh,
                                               const float* __restrict__ W_exp,
                                               const int* __restrict__ topi,
                                               const float* __restrict__ topg,
                                               const float* __restrict__ bias_y,
                                               const float* __restrict__ W_rgb,
                                               const float* __restrict__ b_rgb,
                                               float* __restrict__ buf_sh,
                                               u16* __restrict__ buf_y,
                                               float* __restrict__ out_rgb) {
    __shared__ u16 As[64 * 72];   // A[r][k], stride 72 u16 (144 B, 16B-aligned)
    __shared__ u16 Wt[64 * 72];   // W^T[n][k], stride 72
    int bid = blockIdx.x;
    int kind, row0;
    if (bid < 512) { kind = bid & 1; row0 = (bid >> 1) * 64; }
    else           { kind = 2;       row0 = (bid - 512) * 64; }
    int b = row0 >> 8;
    int tid = threadIdx.x, wv = tid >> 6, lane = tid & 63;
    int m = lane & 15, quad = lane >> 4;

    const float* A = (kind == 2) ? x : dte;
    const float* W0 = (kind == 2) ? W_rgb : W_sh;
    const float* W1 = W0;
    float g0 = 0.f, g1 = 0.f;
    if (kind == 1) {
        W0 = W_exp + (size_t)topi[2 * b] * 49152;
        W1 = W_exp + (size_t)topi[2 * b + 1] * 49152;
        g0 = topg[2 * b]; g1 = topg[2 * b + 1];
    }

    // prefetch registers
    float4 pa[2][2];        // A: 2 chunks x 8 floats
    float  pw[16];          // W: 16 consecutive k for one n
    const int a_r  = tid >> 3;            // A chunk 0 row (chunk 1: +32)
    const int a_k8 = (tid & 7) * 8;       // k offset
    const int w_n  = tid & 63;
    const int w_k0 = (tid >> 6) * 16;

    auto loadA = [&](int kc) {
        #pragma unroll
        for (int j = 0; j < 2; j++) {
            const float* src = A + (size_t)(row0 + a_r + j * 32) * 768 + kc * 64 + a_k8;
            pa[j][0] = *(const float4*)(src);
            pa[j][1] = *(const float4*)(src + 4);
        }
    };
    auto loadW = [&](int kc) {
        if (kind == 1) {
            #pragma unroll
            for (int j = 0; j < 16; j++) {
                size_t off = (size_t)(kc * 64 + w_k0 + j) * 64 + w_n;
                pw[j] = g0 * W0[off] + g1 * W1[off];
            }
        } else {
            #pragma unroll
            for (int j = 0; j < 16; j++)
                pw[j] = W0[(size_t)(kc * 64 + w_k0 + j) * 64 + w_n];
        }
    };
    auto stageLDS = [&]() {
        #pragma unroll
        for (int j = 0; j < 2; j++) {
            uint4 d;
            d.x = pack2(pa[j][0].x, pa[j][0].y);
            d.y = pack2(pa[j][0].z, pa[j][0].w);
            d.z = pack2(pa[j][1].x, pa[j][1].y);
            d.w = pack2(pa[j][1].z, pa[j][1].w);
            *(uint4*)&As[(a_r + j * 32) * 72 + a_k8] = d;
        }
        uint4 d0, d1;
        d0.x = pack2(pw[0],  pw[1]);  d0.y = pack2(pw[2],  pw[3]);
        d0.z = pack2(pw[4],  pw[5]);  d0.w = pack2(pw[6],  pw[7]);
        d1.x = pack2(pw[8],  pw[9]);  d1.y = pack2(pw[10], pw[11]);
        d1.z = pack2(pw[12], pw[13]); d1.w = pack2(pw[14], pw[15]);
        *(uint4*)&Wt[w_n * 72 + w_k0]     = d0;
        *(uint4*)&Wt[w_n * 72 + w_k0 + 8] = d1;
    };

    f32x4 acc0 = {0.f, 0.f, 0.f, 0.f}, acc1 = acc0, acc2 = acc0, acc3 = acc0;

    loadA(0); loadW(0);
    for (int kc = 0; kc < 12; kc++) {
        __syncthreads();            // previous compute done reading LDS
        stageLDS();
        __syncthreads();            // staged data visible
        if (kc < 11) { loadA(kc + 1); loadW(kc + 1); }   // prefetch overlaps MFMAs
        const int ar = (wv * 16 + m) * 72;
        bf16x8 a0 = *(const bf16x8*)&As[ar + quad * 8];
        bf16x8 a1 = *(const bf16x8*)&As[ar + 32 + quad * 8];
        #pragma unroll
        for (int t = 0; t < 4; t++) {
            const int br = (t * 16 + m) * 72;
            bf16x8 b0 = *(const bf16x8*)&Wt[br + quad * 8];
            bf16x8 b1 = *(const bf16x8*)&Wt[br + 32 + quad * 8];
            f32x4* accp = (t == 0) ? &acc0 : (t == 1) ? &acc1 : (t == 2) ? &acc2 : &acc3;
            *accp = __builtin_amdgcn_mfma_f32_16x16x32_bf16(a0, b0, *accp, 0, 0, 0);
            *accp = __builtin_amdgcn_mfma_f32_16x16x32_bf16(a1, b1, *accp, 0, 0, 0);
        }
    }

    // epilogue: C[row0 + wv*16 + quad*4 + i][t*16 + m]
    f32x4 accs[4] = {acc0, acc1, acc2, acc3};
    #pragma unroll
    for (int t = 0; t < 4; t++) {
        int col = t * 16 + m;
        float bias;
        if (kind == 0)      bias = b_sh[col];
        else if (kind == 1) bias = bias_y[b * 64 + col];
        else                bias = b_rgb[col];
        #pragma unroll
        for (int i = 0; i < 4; i++) {
            int r = row0 + wv * 16 + quad * 4 + i;
            float val = accs[t][i] + bias;
            if (kind == 0)      buf_sh[(size_t)r * 64 + col] = val;
            else if (kind == 1) buf_y[(size_t)r * 64 + col] = f2bf(val);
            else                out_rgb[(size_t)r * 64 + col] = val;
        }
    }
}

// ---------- 3. LN + W_px -> t1, t2 (bf16); 16-row tiles, grid 1024 ----------
// (was 32-row/grid-512: only 2 blocks/CU resident -> latency-bound.
//  16-row tiles double resident blocks; LDS 36.6KB -> 4 blocks/CU.)
__global__ __launch_bounds__(256) void k_lnpx(const float* __restrict__ buf_sh,
                                              const float* __restrict__ ln_g,
                                              const float* __restrict__ ln_b,
                                              const float* __restrict__ W_px,
                                              const float* __restrict__ b_px,
                                              u16* __restrict__ t1, u16* __restrict__ t2) {
    __shared__ float T[16 * 68];
    __shared__ float Wpx[8192];
    int r0 = blockIdx.x * 16;
    int tid = threadIdx.x, w = tid >> 6, lane = tid & 63;
    #pragma unroll
    for (int j = 0; j < 8; j++) {
        int e4 = tid + j * 256;
        *(float4*)(Wpx + e4 * 4) = *(const float4*)(W_px + e4 * 4);
    }
    float lnG = ln_g[lane], lnB = ln_b[lane];
    #pragma unroll
    for (int i = 0; i < 4; i++) {
        int l = w * 4 + i;
        float v = buf_sh[(size_t)(r0 + l) * 64 + lane];
        float mean = wsum(v) * (1.f / 64.f);
        float d = v - mean;
        float var = wsum(d * d) * (1.f / 64.f);
        T[l * 68 + lane] = d * rsqrtf(var + 1e-6f) * lnG + lnB;
    }
    __syncthreads();
    int rg = tid >> 4, cg = tid & 15;
    float acc1[4] = {}, acc2[4] = {};
    const float* tr = T + rg * 68;
    #pragma unroll 4
    for (int kk = 0; kk < 64; kk++) {
        float a0 = tr[kk];
        float4 w1 = *(const float4*)(Wpx + kk * 128 + cg * 4);
        float4 w2 = *(const float4*)(Wpx + kk * 128 + 64 + cg * 4);
        acc1[0] += a0 * w1.x; acc1[1] += a0 * w1.y; acc1[2] += a0 * w1.z; acc1[3] += a0 * w1.w;
        acc2[0] += a0 * w2.x; acc2[1] += a0 * w2.y; acc2[2] += a0 * w2.z; acc2[3] += a0 * w2.w;
    }
    float4 b1 = *(const float4*)(b_px + cg * 4);
    float4 b2 = *(const float4*)(b_px + 64 + cg * 4);
    {
        int r = r0 + rg;
        u32* d1 = (u32*)(t1 + (size_t)r * 64 + cg * 4);
        d1[0] = pack2(acc1[0] + b1.x, acc1[1] + b1.y);
        d1[1] = pack2(acc1[2] + b1.z, acc1[3] + b1.w);
        u32* d2 = (u32*)(t2 + (size_t)r * 64 + cg * 4);
        d2[0] = pack2(acc2[0] + b2.x, acc2[1] + b2.y);
        d2[1] = pack2(acc2[2] + b2.z, acc2[3] + b2.w);
    }
}

// ---------- 4. tail; 16-row tiles, grid 1024, 5 phases / 4 syncs ----------
// Was: 32-row/grid-512 (2 blocks/CU, 21% occupancy, 7 serial phases) ->
// latency-bound at 10x roofline (VALUBusy 18.6%, HBM 2.6%, MfmaUtil 0).
// Now: independent loads (buf_y, out-residual+gelu, conv) issue in one
// phase into dedicated LDS buffers; 16-row tile -> 4 blocks/CU resident.
// FMA ordering per output unchanged -> bit-identical numerics.
__global__ __launch_bounds__(256) void k_tail(const u16* __restrict__ t1,
                                              const u16* __restrict__ t2,
                                              const float* __restrict__ conv_sh,
                                              const float* __restrict__ W_pxx,
                                              const float* __restrict__ b_pxx,
                                              const float* __restrict__ buf_sh,
                                              const u16* __restrict__ buf_y,
                                              const float* __restrict__ W_dte,
                                              const float* __restrict__ b_dte,
                                              const float* __restrict__ W_dteall,
                                              const float* __restrict__ b_dteall,
                                              const float* __restrict__ W_fx,
                                              const float* __restrict__ b_fx,
                                              const float* __restrict__ W_fmod,
                                              const float* __restrict__ b_fmod,
                                              const float* __restrict__ W_fxx,
                                              const float* __restrict__ b_fxx,
                                              float* __restrict__ out) {
    __shared__ float C0[16 * 68];   // conv*t2 product; reused as P in phase D
    __shared__ float Yb[16 * 68];   // buf_y as f32
    __shared__ float GA[16 * 68];   // gelu(out residual)
    __shared__ float SH1[16 * 68];  // pxx GEMM + shortcut
    __shared__ float GM[16 * 68];   // gelu(dte_tok)
    __shared__ float RS[16 * 64];   // out residual
    int r0 = blockIdx.x * 16;
    int tid = threadIdx.x, w = tid >> 6, lane = tid & 63;
    int rg = tid >> 4, cg = tid & 15;

    // ---- phase A: three independent loads/compute, one sync ----
    {   // buf_y -> Yb (1024 elems, 4 u16/thread)
        int l = tid >> 4, c = (tid & 15) * 4;
        uint2 v = *(const uint2*)(buf_y + (size_t)(r0 + l) * 64 + c);
        Yb[l * 68 + c + 0] = bf2f((u16)(v.x & 0xffffu));
        Yb[l * 68 + c + 1] = bf2f((u16)(v.x >> 16));
        Yb[l * 68 + c + 2] = bf2f((u16)(v.y & 0xffffu));
        Yb[l * 68 + c + 3] = bf2f((u16)(v.y >> 16));
    }
    {   // out residual -> RS, gelu -> GA (256 float4)
        int l = tid >> 4, c4 = tid & 15;
        float4 rv = *(const float4*)(out + (size_t)(r0 + l) * 64 + c4 * 4);
        *(float4*)(RS + l * 64 + c4 * 4) = rv;
        GA[l * 68 + c4 * 4 + 0] = gelu_f(rv.x);
        GA[l * 68 + c4 * 4 + 1] = gelu_f(rv.y);
        GA[l * 68 + c4 * 4 + 2] = gelu_f(rv.z);
        GA[l * 68 + c4 * 4 + 3] = gelu_f(rv.w);
    }
    {   // depthwise 3x3 conv on t1, * gelu -> C0 (4 rows/wave)
        float c0 = conv_sh[lane * 9 + 0], c1 = conv_sh[lane * 9 + 1], c2 = conv_sh[lane * 9 + 2];
        float c3 = conv_sh[lane * 9 + 3], c4 = conv_sh[lane * 9 + 4], c5 = conv_sh[lane * 9 + 5];
        float c6 = conv_sh[lane * 9 + 6], c7 = conv_sh[lane * 9 + 7], c8 = conv_sh[lane * 9 + 8];
        #pragma unroll
        for (int i = 0; i < 4; i++) {
            int l = w * 4 + i;
            int gr = r0 + l;
            int pix = gr & 255, ii = pix >> 4, jj = pix & 15;
            const u16* p = t1 + (size_t)gr * 64 + lane;
            float c = c4 * bf2f(p[0]);
            if (ii > 0) {
                c += c1 * bf2f(p[-1024]);
                if (jj > 0)  c += c0 * bf2f(p[-1024 - 64]);
                if (jj < 15) c += c2 * bf2f(p[-1024 + 64]);
            }
            if (jj > 0)  c += c3 * bf2f(p[-64]);
            if (jj < 15) c += c5 * bf2f(p[64]);
            if (ii < 15) {
                c += c7 * bf2f(p[1024]);
                if (jj > 0)  c += c6 * bf2f(p[1024 - 64]);
                if (jj < 15) c += c8 * bf2f(p[1024 + 64]);
            }
            C0[l * 68 + lane] = gelu_f(c) * bf2f(t2[(size_t)gr * 64 + lane]);
        }
    }
    __syncthreads();

    // ---- phase B: SH1 = C0 @ W_pxx + b_pxx + buf_sh ----
    {
        float acc[4] = {};
        const float* ur = C0 + rg * 68;
        #pragma unroll 8
        for (int kk = 0; kk < 64; kk++) {
            float a0 = ur[kk];
            float4 wvv = *(const float4*)(W_pxx + kk * 64 + cg * 4);
            acc[0] += a0 * wvv.x; acc[1] += a0 * wvv.y; acc[2] += a0 * wvv.z; acc[3] += a0 * wvv.w;
        }
        float4 bp = *(const float4*)(b_pxx + cg * 4);
        float4 shv = *(const float4*)(buf_sh + (size_t)(r0 + rg) * 64 + cg * 4);
        *(float4*)(SH1 + rg * 68 + cg * 4) =
            make_float4(acc[0] + bp.x + shv.x, acc[1] + bp.y + shv.y,
                        acc[2] + bp.z + shv.z, acc[3] + bp.w + shv.w);
    }
    __syncthreads();

    // ---- phase C: GM = gelu(Yb @ W_dte + SH1 @ W_dteall + biases) ----
    {
        float acc[4] = {};
        const float* yr = Yb + rg * 68;
        const float* sr = SH1 + rg * 68;
        #pragma unroll 4
        for (int kk = 0; kk < 64; kk++) {
            float y0 = yr[kk];
            float s0 = sr[kk];
            float4 w1 = *(const float4*)(W_dte + kk * 64 + cg * 4);
            float4 w2 = *(const float4*)(W_dteall + kk * 64 + cg * 4);
            acc[0] += y0 * w1.x + s0 * w2.x; acc[1] += y0 * w1.y + s0 * w2.y;
            acc[2] += y0 * w1.z + s0 * w2.z; acc[3] += y0 * w1.w + s0 * w2.w;
        }
        float4 bd1 = *(const float4*)(b_dte + cg * 4);
        float4 bd2 = *(const float4*)(b_dteall + cg * 4);
        *(float4*)(GM + rg * 68 + cg * 4) =
            make_float4(gelu_f(acc[0] + bd1.x + bd2.x), gelu_f(acc[1] + bd1.y + bd2.y),
                        gelu_f(acc[2] + bd1.z + bd2.z), gelu_f(acc[3] + bd1.w + bd2.w));
    }
    __syncthreads();

    // ---- phase D: P (into C0) = gelu(GM @ W_fmod + bm) * (GA @ W_fx + bx) ----
    {
        float accA[4] = {}, accM[4] = {};
        const float* ga = GA + rg * 68;
        const float* gm = GM + rg * 68;
        #pragma unroll 4
        for (int kk = 0; kk < 64; kk++) {
            float a0 = ga[kk];
            float m0 = gm[kk];
            float4 wa = *(const float4*)(W_fx + kk * 64 + cg * 4);
            float4 wm = *(const float4*)(W_fmod + kk * 64 + cg * 4);
            accA[0] += a0 * wa.x; accA[1] += a0 * wa.y; accA[2] += a0 * wa.z; accA[3] += a0 * wa.w;
            accM[0] += m0 * wm.x; accM[1] += m0 * wm.y; accM[2] += m0 * wm.z; accM[3] += m0 * wm.w;
        }
        float4 bx = *(const float4*)(b_fx + cg * 4);
        float4 bm = *(const float4*)(b_fmod + cg * 4);
        float a0 = accA[0] + bx.x, a1 = accA[1] + bx.y, a2 = accA[2] + bx.z, a3 = accA[3] + bx.w;
        float m0 = accM[0] + bm.x, m1 = accM[1] + bm.y, m2 = accM[2] + bm.z, m3 = accM[3] + bm.w;
        *(float4*)(C0 + rg * 68 + cg * 4) =
            make_float4(gelu_f(m0) * a0, gelu_f(m1) * a1, gelu_f(m2) * a2, gelu_f(m3) * a3);
    }
    __syncthreads();

    // ---- phase E: out = P @ W_fxx + b_fxx + RS ----
    {
        float acc[4] = {};
        const float* pr = C0 + rg * 68;
        #pragma unroll 8
        for (int kk = 0; kk < 64; kk++) {
            float p0 = pr[kk];
            float4 wvv = *(const float4*)(W_fxx + kk * 64 + cg * 4);
            acc[0] += p0 * wvv.x; acc[1] += p0 * wvv.y; acc[2] += p0 * wvv.z; acc[3] += p0 * wvv.w;
        }
        float4 bo = *(const float4*)(b_fxx + cg * 4);
        *(float4*)(out + (size_t)(r0 + rg) * 64 + cg * 4) =
            make_float4(acc[0] + bo.x + RS[rg * 64 + cg * 4 + 0],
                        acc[1] + bo.y + RS[rg * 64 + cg * 4 + 1],
                        acc[2] + bo.z + RS[rg * 64 + cg * 4 + 2],
                        acc[3] + bo.w + RS[rg * 64 + cg * 4 + 3]);
    }
}

extern "C" void kernel_launch(void* const* d_in, const int* in_sizes, int n_in,
                              void* d_out, int out_size, void* d_ws, size_t ws_size,
                              hipStream_t stream) {
    const float* x       = (const float*)d_in[0];
    const float* dte     = (const float*)d_in[1];
    const float* w_gate  = (const float*)d_in[2];
    const float* W_exp   = (const float*)d_in[3];
    const float* b_exp   = (const float*)d_in[4];
    const float* W_sh    = (const float*)d_in[5];
    const float* b_sh    = (const float*)d_in[6];
    const float* ln_g    = (const float*)d_in[7];
    const float* ln_b    = (const float*)d_in[8];
    const float* W_px    = (const float*)d_in[9];
    const float* b_px    = (const float*)d_in[10];
    const float* conv_sh = (const float*)d_in[11];
    const float* W_pxx   = (const float*)d_in[12];
    const float* b_pxx   = (const float*)d_in[13];
    const float* W_dte   = (const float*)d_in[14];
    const float* b_dte   = (const float*)d_in[15];
    const float* W_dteall= (const float*)d_in[16];
    const float* b_dteall= (const float*)d_in[17];
    const float* W_rgb   = (const float*)d_in[18];
    const float* b_rgb   = (const float*)d_in[19];
    const float* W_fx    = (const float*)d_in[20];
    const float* b_fx    = (const float*)d_in[21];
    const float* W_fmod  = (const float*)d_in[22];
    const float* b_fmod  = (const float*)d_in[23];
    const float* W_fxx   = (const float*)d_in[24];
    const float* b_fxx   = (const float*)d_in[25];

    float* out = (float*)d_out;     // [0,1048576) plane + loss at [1048576]

    float* wsf    = (float*)d_ws;
    float* partial= wsf;                         // 2048
    int*   topi   = (int*)(wsf + 2048);          // 128
    float* topg   = wsf + 2176;                  // 128
    float* bias_y = wsf + 2304;                  // 4096
    float* buf_sh = wsf + 8192;                  // 1048576 f32
    u16*   buf_y  = (u16*)(wsf + 8192 + 1048576);
    u16*   t1     = (u16*)(wsf + 8192 + 1048576 + 524288);
    u16*   t2     = (u16*)(wsf + 8192 + 1048576 + 524288*2);

    hipLaunchKernelGGL(k_gate_part, dim3(256), dim3(256), 0, stream, dte, w_gate, partial);
    hipLaunchKernelGGL(k_gate_fin, dim3(1), dim3(256), 0, stream,
                       partial, b_exp, topi, topg, bias_y, out + 1048576);
    hipLaunchKernelGGL(k_gemm3, dim3(768), dim3(256), 0, stream,
                       dte, x, W_sh, b_sh, W_exp, topi, topg, bias_y, W_rgb, b_rgb,
                       buf_sh, buf_y, out);
    hipLaunchKernelGGL(k_lnpx, dim3(1024), dim3(256), 0, stream,
                       buf_sh, ln_g, ln_b, W_px, b_px, t1, t2);
    hipLaunchKernelGGL(k_tail, dim3(1024), dim3(256), 0, stream,
                       t1, t2, conv_sh, W_pxx, b_pxx, buf_sh, buf_y,
                       W_dte, b_dte, W_dteall, b_dteall,
                       W_fx, b_fx, W_fmod, b_fmod, W_fxx, b_fxx, out);

    (void)in_sizes; (void)n_in; (void)out_size; (void)ws_size;
}

// Round 2
// 258.555 us; speedup vs baseline: 1.0344x; 1.0344x over previous
//
#include <hip/hip_runtime.h>
#include <math.h>

typedef unsigned short u16;
typedef unsigned int u32;
typedef __attribute__((ext_vector_type(8))) short bf16x8;
typedef __attribute__((ext_vector_type(4))) float f32x4;

// B=64, L=256, DIN=768, H=64, E=8, K=2, S=16; BL=16384. All inputs f32, output f32.

__device__ __forceinline__ float bf2f(u16 u) {
    union { u32 i; float f; } x; x.i = ((u32)u) << 16; return x.f;
}
__device__ __forceinline__ u16 f2bf(float f) {
    union { float f; u32 i; } x; x.f = f;
    u32 i = x.i;
    return (u16)((i + 0x7fffu + ((i >> 16) & 1u)) >> 16);
}
__device__ __forceinline__ u32 pack2(float a, float b) {
    return (u32)f2bf(a) | ((u32)f2bf(b) << 16);
}
__device__ __forceinline__ float wsum(float v) {
    #pragma unroll
    for (int o = 1; o < 64; o <<= 1) v += __shfl_xor(v, o, 64);
    return v;
}
__device__ __forceinline__ float gelu_f(float x) {
    return 0.5f * x * (1.0f + erff(x * 0.70710678118654752440f));
}

// ---------- 1a. partial gating ----------
__global__ __launch_bounds__(256) void k_gate_part(const float* __restrict__ dte,
                                                   const float* __restrict__ w_gate,
                                                   float* __restrict__ partial) {
    __shared__ float dmeanS[64];
    int p = blockIdx.x, tid = threadIdx.x, w = tid >> 6, lane = tid & 63;
    for (int i = 0; i < 16; i++) {
        int l = w * 16 + i;
        const float* pr = dte + ((size_t)p * 64 + l) * 768;
        float s = 0.f;
        #pragma unroll
        for (int j = 0; j < 3; j++) {
            float4 v = *(const float4*)(pr + (lane + j * 64) * 4);
            s += v.x + v.y + v.z + v.w;
        }
        s = wsum(s);
        if (lane == 0) dmeanS[l] = s * (1.f / 768.f);
    }
    __syncthreads();
    if (w == 0) {
        float dm = dmeanS[lane];
        int wl = (p & 3) * 64 + lane;
        #pragma unroll
        for (int e = 0; e < 8; e++) {
            float s = wsum(dm * w_gate[wl * 8 + e]);
            if (lane == 0) partial[p * 8 + e] = s;
        }
    }
}

// ---------- 1b. finalize gates + loss ----------
__global__ __launch_bounds__(256) void k_gate_fin(const float* __restrict__ partial,
                                                  const float* __restrict__ b_exp,
                                                  int* __restrict__ topi,
                                                  float* __restrict__ topg,
                                                  float* __restrict__ bias_y,
                                                  float* __restrict__ loss_out) {
    __shared__ float gS[64 * 8];
    __shared__ int i0S[64], i1S[64];
    __shared__ float g0S[64], g1S[64];
    int tid = threadIdx.x;
    if (tid < 64) {
        float lg[8];
        #pragma unroll
        for (int e = 0; e < 8; e++)
            lg[e] = partial[(tid * 4 + 0) * 8 + e] + partial[(tid * 4 + 1) * 8 + e] +
                    partial[(tid * 4 + 2) * 8 + e] + partial[(tid * 4 + 3) * 8 + e];
        int i0 = 0; float v0 = lg[0];
        #pragma unroll
        for (int e = 1; e < 8; e++) if (lg[e] > v0) { v0 = lg[e]; i0 = e; }
        int i1 = -1; float v1 = -1e30f;
        #pragma unroll
        for (int e = 0; e < 8; e++) if (e != i0 && lg[e] > v1) { v1 = lg[e]; i1 = e; }
        if (i1 < 0) i1 = (i0 + 1) & 7;
        float e2 = expf(v1 - v0);
        float g0 = 1.f / (1.f + e2);
        float g1 = e2 / (1.f + e2);
        #pragma unroll
        for (int e = 0; e < 8; e++) gS[tid * 8 + e] = 0.f;
        gS[tid * 8 + i0] = g0;
        gS[tid * 8 + i1] = g1;
        i0S[tid] = i0; i1S[tid] = i1; g0S[tid] = g0; g1S[tid] = g1;
        topi[tid * 2] = i0; topi[tid * 2 + 1] = i1;
        topg[tid * 2] = g0; topg[tid * 2 + 1] = g1;
    }
    __syncthreads();
    for (int idx = tid; idx < 4096; idx += 256) {
        int b = idx >> 6, h = idx & 63;
        bias_y[idx] = g0S[b] * b_exp[i0S[b] * 64 + h] + g1S[b] * b_exp[i1S[b] * 64 + h];
    }
    if (tid < 64) {
        float g[8];
        #pragma unroll
        for (int e = 0; e < 8; e++) g[e] = gS[tid * 8 + e];
        float imp[8], ld[8];
        #pragma unroll
        for (int e = 0; e < 8; e++) {
            imp[e] = wsum(g[e]);
            ld[e]  = wsum(g[e] > 0.f ? 1.f : 0.f);
        }
        if (tid == 0) {
            float l = 0.f;
            {
                float s = 0.f;
                #pragma unroll
                for (int e = 0; e < 8; e++) s += imp[e];
                float mn = s / 8.f, v = 0.f;
                #pragma unroll
                for (int e = 0; e < 8; e++) { float d = imp[e] - mn; v += d * d; }
                l += (v / 7.f) / (mn * mn + 1e-10f);
            }
            {
                float s = 0.f;
                #pragma unroll
                for (int e = 0; e < 8; e++) s += ld[e];
                float mn = s / 8.f, v = 0.f;
                #pragma unroll
                for (int e = 0; e < 8; e++) { float d = ld[e] - mn; v += d * d; }
                l += (v / 7.f) / (mn * mn + 1e-10f);
            }
            loss_out[0] = 0.01f * l;
        }
    }
}

// ---------- 2. MFMA GEMMs, BK=64, conflict-free staging, register prefetch.
//   bid<512: pair=(bid>>1) rows, kind=bid&1 (0=sh f32, 1=y bf16);
//   bid>=512: kind2 rgb -> out plane. ----------
__global__ __launch_bounds__(256) void k_gemm3(const float* __restrict__ dte,
                                               const float* __restrict__ x,
                                               const float* __restrict__ W_sh,
                                               const float* __restrict__ b_sh,
                                               const float* __restrict__ W_exp,
                                               const int* __restrict__ topi,
                                               const float* __restrict__ topg,
                                               const float* __restrict__ bias_y,
                                               const float* __restrict__ W_rgb,
                                               const float* __restrict__ b_rgb,
                                               float* __restrict__ buf_sh,
                                               u16* __restrict__ buf_y,
                                               float* __restrict__ out_rgb) {
    __shared__ u16 As[64 * 72];   // A[r][k], stride 72 u16 (144 B, 16B-aligned)
    __shared__ u16 Wt[64 * 72];   // W^T[n][k], stride 72
    int bid = blockIdx.x;
    int kind, row0;
    if (bid < 512) { kind = bid & 1; row0 = (bid >> 1) * 64; }
    else           { kind = 2;       row0 = (bid - 512) * 64; }
    int b = row0 >> 8;
    int tid = threadIdx.x, wv = tid >> 6, lane = tid & 63;
    int m = lane & 15, quad = lane >> 4;

    const float* A = (kind == 2) ? x : dte;
    const float* W0 = (kind == 2) ? W_rgb : W_sh;
    const float* W1 = W0;
    float g0 = 0.f, g1 = 0.f;
    if (kind == 1) {
        W0 = W_exp + (size_t)topi[2 * b] * 49152;
        W1 = W_exp + (size_t)topi[2 * b + 1] * 49152;
        g0 = topg[2 * b]; g1 = topg[2 * b + 1];
    }

    // prefetch registers
    float4 pa[2][2];        // A: 2 chunks x 8 floats
    float  pw[16];          // W: 16 consecutive k for one n
    const int a_r  = tid >> 3;            // A chunk 0 row (chunk 1: +32)
    const int a_k8 = (tid & 7) * 8;       // k offset
    const int w_n  = tid & 63;
    const int w_k0 = (tid >> 6) * 16;

    auto loadA = [&](int kc) {
        #pragma unroll
        for (int j = 0; j < 2; j++) {
            const float* src = A + (size_t)(row0 + a_r + j * 32) * 768 + kc * 64 + a_k8;
            pa[j][0] = *(const float4*)(src);
            pa[j][1] = *(const float4*)(src + 4);
        }
    };
    auto loadW = [&](int kc) {
        if (kind == 1) {
            #pragma unroll
            for (int j = 0; j < 16; j++) {
                size_t off = (size_t)(kc * 64 + w_k0 + j) * 64 + w_n;
                pw[j] = g0 * W0[off] + g1 * W1[off];
            }
        } else {
            #pragma unroll
            for (int j = 0; j < 16; j++)
                pw[j] = W0[(size_t)(kc * 64 + w_k0 + j) * 64 + w_n];
        }
    };
    auto stageLDS = [&]() {
        #pragma unroll
        for (int j = 0; j < 2; j++) {
            uint4 d;
            d.x = pack2(pa[j][0].x, pa[j][0].y);
            d.y = pack2(pa[j][0].z, pa[j][0].w);
            d.z = pack2(pa[j][1].x, pa[j][1].y);
            d.w = pack2(pa[j][1].z, pa[j][1].w);
            *(uint4*)&As[(a_r + j * 32) * 72 + a_k8] = d;
        }
        uint4 d0, d1;
        d0.x = pack2(pw[0],  pw[1]);  d0.y = pack2(pw[2],  pw[3]);
        d0.z = pack2(pw[4],  pw[5]);  d0.w = pack2(pw[6],  pw[7]);
        d1.x = pack2(pw[8],  pw[9]);  d1.y = pack2(pw[10], pw[11]);
        d1.z = pack2(pw[12], pw[13]); d1.w = pack2(pw[14], pw[15]);
        *(uint4*)&Wt[w_n * 72 + w_k0]     = d0;
        *(uint4*)&Wt[w_n * 72 + w_k0 + 8] = d1;
    };

    f32x4 acc0 = {0.f, 0.f, 0.f, 0.f}, acc1 = acc0, acc2 = acc0, acc3 = acc0;

    loadA(0); loadW(0);
    for (int kc = 0; kc < 12; kc++) {
        __syncthreads();            // previous compute done reading LDS
        stageLDS();
        __syncthreads();            // staged data visible
        if (kc < 11) { loadA(kc + 1); loadW(kc + 1); }   // prefetch overlaps MFMAs
        const int ar = (wv * 16 + m) * 72;
        bf16x8 a0 = *(const bf16x8*)&As[ar + quad * 8];
        bf16x8 a1 = *(const bf16x8*)&As[ar + 32 + quad * 8];
        #pragma unroll
        for (int t = 0; t < 4; t++) {
            const int br = (t * 16 + m) * 72;
            bf16x8 b0 = *(const bf16x8*)&Wt[br + quad * 8];
            bf16x8 b1 = *(const bf16x8*)&Wt[br + 32 + quad * 8];
            f32x4* accp = (t == 0) ? &acc0 : (t == 1) ? &acc1 : (t == 2) ? &acc2 : &acc3;
            *accp = __builtin_amdgcn_mfma_f32_16x16x32_bf16(a0, b0, *accp, 0, 0, 0);
            *accp = __builtin_amdgcn_mfma_f32_16x16x32_bf16(a1, b1, *accp, 0, 0, 0);
        }
    }

    // epilogue: C[row0 + wv*16 + quad*4 + i][t*16 + m]
    f32x4 accs[4] = {acc0, acc1, acc2, acc3};
    #pragma unroll
    for (int t = 0; t < 4; t++) {
        int col = t * 16 + m;
        float bias;
        if (kind == 0)      bias = b_sh[col];
        else if (kind == 1) bias = bias_y[b * 64 + col];
        else                bias = b_rgb[col];
        #pragma unroll
        for (int i = 0; i < 4; i++) {
            int r = row0 + wv * 16 + quad * 4 + i;
            float val = accs[t][i] + bias;
            if (kind == 0)      buf_sh[(size_t)r * 64 + col] = val;
            else if (kind == 1) buf_y[(size_t)r * 64 + col] = f2bf(val);
            else                out_rgb[(size_t)r * 64 + col] = val;
        }
    }
}

// ---------- 3. LN + W_px -> t1, t2 (bf16); 32-row tiles, grid 512 ----------
// (round-0 version restored: weights already staged in LDS here; the 16-row
//  variant doubled per-row W_px staging traffic and regressed ~12 µs.)
__global__ __launch_bounds__(256) void k_lnpx(const float* __restrict__ buf_sh,
                                              const float* __restrict__ ln_g,
                                              const float* __restrict__ ln_b,
                                              const float* __restrict__ W_px,
                                              const float* __restrict__ b_px,
                                              u16* __restrict__ t1, u16* __restrict__ t2) {
    __shared__ float T[32 * 68];
    __shared__ float Wpx[8192];
    int r0 = blockIdx.x * 32;
    int tid = threadIdx.x, w = tid >> 6, lane = tid & 63;
    #pragma unroll
    for (int j = 0; j < 8; j++) {
        int e4 = tid + j * 256;
        *(float4*)(Wpx + e4 * 4) = *(const float4*)(W_px + e4 * 4);
    }
    float lnG = ln_g[lane], lnB = ln_b[lane];
    for (int i = 0; i < 8; i++) {
        int l = w * 8 + i;
        float v = buf_sh[(size_t)(r0 + l) * 64 + lane];
        float mean = wsum(v) * (1.f / 64.f);
        float d = v - mean;
        float var = wsum(d * d) * (1.f / 64.f);
        T[l * 68 + lane] = d * rsqrtf(var + 1e-6f) * lnG + lnB;
    }
    __syncthreads();
    int rg = tid >> 4, cg = tid & 15;
    float acc1[2][4] = {}, acc2[2][4] = {};
    const float* tr = T + rg * 2 * 68;
    #pragma unroll 4
    for (int kk = 0; kk < 64; kk++) {
        float a0 = tr[kk], a1 = tr[68 + kk];
        float4 w1 = *(const float4*)(Wpx + kk * 128 + cg * 4);
        float4 w2 = *(const float4*)(Wpx + kk * 128 + 64 + cg * 4);
        acc1[0][0] += a0 * w1.x; acc1[0][1] += a0 * w1.y; acc1[0][2] += a0 * w1.z; acc1[0][3] += a0 * w1.w;
        acc1[1][0] += a1 * w1.x; acc1[1][1] += a1 * w1.y; acc1[1][2] += a1 * w1.z; acc1[1][3] += a1 * w1.w;
        acc2[0][0] += a0 * w2.x; acc2[0][1] += a0 * w2.y; acc2[0][2] += a0 * w2.z; acc2[0][3] += a0 * w2.w;
        acc2[1][0] += a1 * w2.x; acc2[1][1] += a1 * w2.y; acc2[1][2] += a1 * w2.z; acc2[1][3] += a1 * w2.w;
    }
    float4 b1 = *(const float4*)(b_px + cg * 4);
    float4 b2 = *(const float4*)(b_px + 64 + cg * 4);
    #pragma unroll
    for (int i = 0; i < 2; i++) {
        int r = r0 + rg * 2 + i;
        u32* d1 = (u32*)(t1 + (size_t)r * 64 + cg * 4);
        d1[0] = pack2(acc1[i][0] + b1.x, acc1[i][1] + b1.y);
        d1[1] = pack2(acc1[i][2] + b1.z, acc1[i][3] + b1.w);
        u32* d2 = (u32*)(t2 + (size_t)r * 64 + cg * 4);
        d2[0] = pack2(acc2[i][0] + b2.x, acc2[i][1] + b2.y);
        d2[1] = pack2(acc2[i][2] + b2.z, acc2[i][3] + b2.w);
    }
}

// ---------- 4. tail; weights staged in LDS (ping-pong), 16-row tiles ----------
// Round-1 diagnosis: each GEMM phase re-read its 16 KB weight matrix 16x per
// block through L1 (256 KB/block/matrix) -> L1-BW-bound at VALUBusy 16%.
// Now: each matrix staged to LDS ONCE per block (16 KB, coalesced), next
// phase's weights load during current phase's compute (2-half ping-pong;
// T14 issue-early/write-late). Two-matrix phases split into two sub-phases
// accumulating into persistent registers; per-accumulator FMA order kept.
// LDS 51.3 KB -> 3 blocks/CU.
__global__ __launch_bounds__(256) void k_tail(const u16* __restrict__ t1,
                                              const u16* __restrict__ t2,
                                              const float* __restrict__ conv_sh,
                                              const float* __restrict__ W_pxx,
                                              const float* __restrict__ b_pxx,
                                              const float* __restrict__ buf_sh,
                                              const u16* __restrict__ buf_y,
                                              const float* __restrict__ W_dte,
                                              const float* __restrict__ b_dte,
                                              const float* __restrict__ W_dteall,
                                              const float* __restrict__ b_dteall,
                                              const float* __restrict__ W_fx,
                                              const float* __restrict__ b_fx,
                                              const float* __restrict__ W_fmod,
                                              const float* __restrict__ b_fmod,
                                              const float* __restrict__ W_fxx,
                                              const float* __restrict__ b_fxx,
                                              float* __restrict__ out) {
    __shared__ float C0[16 * 68];   // conv*t2 product; reused as P in phase D2
    __shared__ float GA[16 * 68];   // gelu(out residual)
    __shared__ float SH1[16 * 68];  // pxx GEMM + shortcut
    __shared__ float GM[16 * 68];   // gelu(dte_tok)
    __shared__ u16   Ybh[16 * 72];  // buf_y (bf16, raw copy)
    __shared__ float WL[2][4096];   // ping-pong 16 KB weight tiles
    int r0 = blockIdx.x * 16;
    int tid = threadIdx.x, w = tid >> 6, lane = tid & 63;
    int rg = tid >> 4, cg = tid & 15;

    float4 wbuf[4];
    auto wload = [&](const float* Wsrc) {
        #pragma unroll
        for (int j = 0; j < 4; j++)
            wbuf[j] = *(const float4*)(Wsrc + (tid + j * 256) * 4);
    };
    auto wstore = [&](int half) {
        #pragma unroll
        for (int j = 0; j < 4; j++)
            *(float4*)(&WL[half][(tid + j * 256) * 4]) = wbuf[j];
    };

    // ---- phase A: stage W_pxx -> WL0; Yb copy; residual+gelu; conv ----
    wload(W_pxx);
    float4 rsv;
    {   // buf_y raw bf16 copy (this thread's 4 elems)
        uint2 v = *(const uint2*)(buf_y + (size_t)(r0 + rg) * 64 + cg * 4);
        *(uint2*)(&Ybh[rg * 72 + cg * 4]) = v;
    }
    {   // out residual -> registers; gelu -> GA
        rsv = *(const float4*)(out + (size_t)(r0 + rg) * 64 + cg * 4);
        GA[rg * 68 + cg * 4 + 0] = gelu_f(rsv.x);
        GA[rg * 68 + cg * 4 + 1] = gelu_f(rsv.y);
        GA[rg * 68 + cg * 4 + 2] = gelu_f(rsv.z);
        GA[rg * 68 + cg * 4 + 3] = gelu_f(rsv.w);
    }
    {   // depthwise 3x3 conv on t1, * gelu * t2 -> C0 (4 rows/wave)
        float c0 = conv_sh[lane * 9 + 0], c1 = conv_sh[lane * 9 + 1], c2 = conv_sh[lane * 9 + 2];
        float c3 = conv_sh[lane * 9 + 3], c4 = conv_sh[lane * 9 + 4], c5 = conv_sh[lane * 9 + 5];
        float c6 = conv_sh[lane * 9 + 6], c7 = conv_sh[lane * 9 + 7], c8 = conv_sh[lane * 9 + 8];
        #pragma unroll
        for (int i = 0; i < 4; i++) {
            int l = w * 4 + i;
            int gr = r0 + l;
            int pix = gr & 255, ii = pix >> 4, jj = pix & 15;
            const u16* p = t1 + (size_t)gr * 64 + lane;
            float c = c4 * bf2f(p[0]);
            if (ii > 0) {
                c += c1 * bf2f(p[-1024]);
                if (jj > 0)  c += c0 * bf2f(p[-1024 - 64]);
                if (jj < 15) c += c2 * bf2f(p[-1024 + 64]);
            }
            if (jj > 0)  c += c3 * bf2f(p[-64]);
            if (jj < 15) c += c5 * bf2f(p[64]);
            if (ii < 15) {
                c += c7 * bf2f(p[1024]);
                if (jj > 0)  c += c6 * bf2f(p[1024 - 64]);
                if (jj < 15) c += c8 * bf2f(p[1024 + 64]);
            }
            C0[l * 68 + lane] = gelu_f(c) * bf2f(t2[(size_t)gr * 64 + lane]);
        }
    }
    wstore(0);
    __syncthreads();

    // ---- phase B: SH1 = C0 @ W_pxx(WL0) + b_pxx + buf_sh; stage W_dte -> WL1 ----
    wload(W_dte);
    {
        float acc[4] = {};
        const float* ur = C0 + rg * 68;
        #pragma unroll 8
        for (int kk = 0; kk < 64; kk++) {
            float a0 = ur[kk];
            float4 wv = *(const float4*)(&WL[0][kk * 64 + cg * 4]);
            acc[0] += a0 * wv.x; acc[1] += a0 * wv.y; acc[2] += a0 * wv.z; acc[3] += a0 * wv.w;
        }
        float4 bp = *(const float4*)(b_pxx + cg * 4);
        float4 shv = *(const float4*)(buf_sh + (size_t)(r0 + rg) * 64 + cg * 4);
        *(float4*)(SH1 + rg * 68 + cg * 4) =
            make_float4(acc[0] + bp.x + shv.x, acc[1] + bp.y + shv.y,
                        acc[2] + bp.z + shv.z, acc[3] + bp.w + shv.w);
    }
    wstore(1);
    __syncthreads();

    // ---- phase C1: accC = Yb @ W_dte(WL1); stage W_dteall -> WL0 ----
    float accC[4] = {};
    wload(W_dteall);
    {
        const u16* yr = Ybh + rg * 72;
        #pragma unroll 8
        for (int kk = 0; kk < 64; kk++) {
            float y0 = bf2f(yr[kk]);
            float4 wv = *(const float4*)(&WL[1][kk * 64 + cg * 4]);
            accC[0] += y0 * wv.x; accC[1] += y0 * wv.y; accC[2] += y0 * wv.z; accC[3] += y0 * wv.w;
        }
    }
    wstore(0);
    __syncthreads();

    // ---- phase C2: accC += SH1 @ W_dteall(WL0); GM = gelu(accC + biases);
    //      stage W_fx -> WL1 ----
    wload(W_fx);
    {
        const float* sr = SH1 + rg * 68;
        #pragma unroll 8
        for (int kk = 0; kk < 64; kk++) {
            float s0 = sr[kk];
            float4 wv = *(const float4*)(&WL[0][kk * 64 + cg * 4]);
            accC[0] += s0 * wv.x; accC[1] += s0 * wv.y; accC[2] += s0 * wv.z; accC[3] += s0 * wv.w;
        }
        float4 bd1 = *(const float4*)(b_dte + cg * 4);
        float4 bd2 = *(const float4*)(b_dteall + cg * 4);
        *(float4*)(GM + rg * 68 + cg * 4) =
            make_float4(gelu_f(accC[0] + bd1.x + bd2.x), gelu_f(accC[1] + bd1.y + bd2.y),
                        gelu_f(accC[2] + bd1.z + bd2.z), gelu_f(accC[3] + bd1.w + bd2.w));
    }
    wstore(1);
    __syncthreads();

    // ---- phase D1: accA = GA @ W_fx(WL1); stage W_fmod -> WL0 ----
    float accA[4] = {};
    wload(W_fmod);
    {
        const float* ga = GA + rg * 68;
        #pragma unroll 8
        for (int kk = 0; kk < 64; kk++) {
            float a0 = ga[kk];
            float4 wv = *(const float4*)(&WL[1][kk * 64 + cg * 4]);
            accA[0] += a0 * wv.x; accA[1] += a0 * wv.y; accA[2] += a0 * wv.z; accA[3] += a0 * wv.w;
        }
    }
    wstore(0);
    __syncthreads();

    // ---- phase D2: accM = GM @ W_fmod(WL0); P(C0) = gelu(accM+bm)*(accA+bx);
    //      stage W_fxx -> WL1 ----
    wload(W_fxx);
    {
        float accM[4] = {};
        const float* gm = GM + rg * 68;
        #pragma unroll 8
        for (int kk = 0; kk < 64; kk++) {
            float m0 = gm[kk];
            float4 wv = *(const float4*)(&WL[0][kk * 64 + cg * 4]);
            accM[0] += m0 * wv.x; accM[1] += m0 * wv.y; accM[2] += m0 * wv.z; accM[3] += m0 * wv.w;
        }
        float4 bx = *(const float4*)(b_fx + cg * 4);
        float4 bm = *(const float4*)(b_fmod + cg * 4);
        float a0 = accA[0] + bx.x, a1 = accA[1] + bx.y, a2 = accA[2] + bx.z, a3 = accA[3] + bx.w;
        float m0 = accM[0] + bm.x, m1 = accM[1] + bm.y, m2 = accM[2] + bm.z, m3 = accM[3] + bm.w;
        *(float4*)(C0 + rg * 68 + cg * 4) =
            make_float4(gelu_f(m0) * a0, gelu_f(m1) * a1, gelu_f(m2) * a2, gelu_f(m3) * a3);
    }
    wstore(1);
    __syncthreads();

    // ---- phase E: out = P(C0) @ W_fxx(WL1) + b_fxx + rsv ----
    {
        float acc[4] = {};
        const float* pr = C0 + rg * 68;
        #pragma unroll 8
        for (int kk = 0; kk < 64; kk++) {
            float p0 = pr[kk];
            float4 wv = *(const float4*)(&WL[1][kk * 64 + cg * 4]);
            acc[0] += p0 * wv.x; acc[1] += p0 * wv.y; acc[2] += p0 * wv.z; acc[3] += p0 * wv.w;
        }
        float4 bo = *(const float4*)(b_fxx + cg * 4);
        *(float4*)(out + (size_t)(r0 + rg) * 64 + cg * 4) =
            make_float4(acc[0] + bo.x + rsv.x, acc[1] + bo.y + rsv.y,
                        acc[2] + bo.z + rsv.z, acc[3] + bo.w + rsv.w);
    }
}

extern "C" void kernel_launch(void* const* d_in, const int* in_sizes, int n_in,
                              void* d_out, int out_size, void* d_ws, size_t ws_size,
                              hipStream_t stream) {
    const float* x       = (const float*)d_in[0];
    const float* dte     = (const float*)d_in[1];
    const float* w_gate  = (const float*)d_in[2];
    const float* W_exp   = (const float*)d_in[3];
    const float* b_exp   = (const float*)d_in[4];
    const float* W_sh    = (const float*)d_in[5];
    const float* b_sh    = (const float*)d_in[6];
    const float* ln_g    = (const float*)d_in[7];
    const float* ln_b    = (const float*)d_in[8];
    const float* W_px    = (const float*)d_in[9];
    const float* b_px    = (const float*)d_in[10];
    const float* conv_sh = (const float*)d_in[11];
    const float* W_pxx   = (const float*)d_in[12];
    const float* b_pxx   = (const float*)d_in[13];
    const float* W_dte   = (const float*)d_in[14];
    const float* b_dte   = (const float*)d_in[15];
    const float* W_dteall= (const float*)d_in[16];
    const float* b_dteall= (const float*)d_in[17];
    const float* W_rgb   = (const float*)d_in[18];
    const float* b_rgb   = (const float*)d_in[19];
    const float* W_fx    = (const float*)d_in[20];
    const float* b_fx    = (const float*)d_in[21];
    const float* W_fmod  = (const float*)d_in[22];
    const float* b_fmod  = (const float*)d_in[23];
    const float* W_fxx   = (const float*)d_in[24];
    const float* b_fxx   = (const float*)d_in[25];

    float* out = (float*)d_out;     // [0,1048576) plane + loss at [1048576]

    float* wsf    = (float*)d_ws;
    float* partial= wsf;                         // 2048
    int*   topi   = (int*)(wsf + 2048);          // 128
    float* topg   = wsf + 2176;                  // 128
    float* bias_y = wsf + 2304;                  // 4096
    float* buf_sh = wsf + 8192;                  // 1048576 f32
    u16*   buf_y  = (u16*)(wsf + 8192 + 1048576);
    u16*   t1     = (u16*)(wsf + 8192 + 1048576 + 524288);
    u16*   t2     = (u16*)(wsf + 8192 + 1048576 + 524288*2);

    hipLaunchKernelGGL(k_gate_part, dim3(256), dim3(256), 0, stream, dte, w_gate, partial);
    hipLaunchKernelGGL(k_gate_fin, dim3(1), dim3(256), 0, stream,
                       partial, b_exp, topi, topg, bias_y, out + 1048576);
    hipLaunchKernelGGL(k_gemm3, dim3(768), dim3(256), 0, stream,
                       dte, x, W_sh, b_sh, W_exp, topi, topg, bias_y, W_rgb, b_rgb,
                       buf_sh, buf_y, out);
    hipLaunchKernelGGL(k_lnpx, dim3(512), dim3(256), 0, stream,
                       buf_sh, ln_g, ln_b, W_px, b_px, t1, t2);
    hipLaunchKernelGGL(k_tail, dim3(1024), dim3(256), 0, stream,
                       t1, t2, conv_sh, W_pxx, b_pxx, buf_sh, buf_y,
                       W_dte, b_dte, W_dteall, b_dteall,
                       W_fx, b_fx, W_fmod, b_fmod, W_fxx, b_fxx, out);

    (void)in_sizes; (void)n_in; (void)out_size; (void)ws_size;
}

// Round 4
// 242.182 us; speedup vs baseline: 1.1043x; 1.0676x over previous
//
#include <hip/hip_runtime.h>
#include <math.h>

typedef unsigned short u16;
typedef unsigned int u32;
typedef __attribute__((ext_vector_type(8))) short bf16x8;
typedef __attribute__((ext_vector_type(4))) float f32x4;

// B=64, L=256, DIN=768, H=64, E=8, K=2, S=16; BL=16384. All inputs f32, output f32.

__device__ __forceinline__ float bf2f(u16 u) {
    union { u32 i; float f; } x; x.i = ((u32)u) << 16; return x.f;
}
__device__ __forceinline__ u16 f2bf(float f) {
    union { float f; u32 i; } x; x.f = f;
    u32 i = x.i;
    return (u16)((i + 0x7fffu + ((i >> 16) & 1u)) >> 16);
}
__device__ __forceinline__ u32 pack2(float a, float b) {
    return (u32)f2bf(a) | ((u32)f2bf(b) << 16);
}
__device__ __forceinline__ float wsum(float v) {
    #pragma unroll
    for (int o = 1; o < 64; o <<= 1) v += __shfl_xor(v, o, 64);
    return v;
}
__device__ __forceinline__ float gelu_f(float x) {
    return 0.5f * x * (1.0f + erff(x * 0.70710678118654752440f));
}

// ---------- 1a. partial gating ----------
__global__ __launch_bounds__(256) void k_gate_part(const float* __restrict__ dte,
                                                   const float* __restrict__ w_gate,
                                                   float* __restrict__ partial) {
    __shared__ float dmeanS[64];
    int p = blockIdx.x, tid = threadIdx.x, w = tid >> 6, lane = tid & 63;
    for (int i = 0; i < 16; i++) {
        int l = w * 16 + i;
        const float* pr = dte + ((size_t)p * 64 + l) * 768;
        float s = 0.f;
        #pragma unroll
        for (int j = 0; j < 3; j++) {
            float4 v = *(const float4*)(pr + (lane + j * 64) * 4);
            s += v.x + v.y + v.z + v.w;
        }
        s = wsum(s);
        if (lane == 0) dmeanS[l] = s * (1.f / 768.f);
    }
    __syncthreads();
    if (w == 0) {
        float dm = dmeanS[lane];
        int wl = (p & 3) * 64 + lane;
        #pragma unroll
        for (int e = 0; e < 8; e++) {
            float s = wsum(dm * w_gate[wl * 8 + e]);
            if (lane == 0) partial[p * 8 + e] = s;
        }
    }
}

// ---------- 1b. finalize gates + loss ----------
__global__ __launch_bounds__(256) void k_gate_fin(const float* __restrict__ partial,
                                                  const float* __restrict__ b_exp,
                                                  int* __restrict__ topi,
                                                  float* __restrict__ topg,
                                                  float* __restrict__ bias_y,
                                                  float* __restrict__ loss_out) {
    __shared__ float gS[64 * 8];
    __shared__ int i0S[64], i1S[64];
    __shared__ float g0S[64], g1S[64];
    int tid = threadIdx.x;
    if (tid < 64) {
        float lg[8];
        #pragma unroll
        for (int e = 0; e < 8; e++)
            lg[e] = partial[(tid * 4 + 0) * 8 + e] + partial[(tid * 4 + 1) * 8 + e] +
                    partial[(tid * 4 + 2) * 8 + e] + partial[(tid * 4 + 3) * 8 + e];
        int i0 = 0; float v0 = lg[0];
        #pragma unroll
        for (int e = 1; e < 8; e++) if (lg[e] > v0) { v0 = lg[e]; i0 = e; }
        int i1 = -1; float v1 = -1e30f;
        #pragma unroll
        for (int e = 0; e < 8; e++) if (e != i0 && lg[e] > v1) { v1 = lg[e]; i1 = e; }
        if (i1 < 0) i1 = (i0 + 1) & 7;
        float e2 = expf(v1 - v0);
        float g0 = 1.f / (1.f + e2);
        float g1 = e2 / (1.f + e2);
        #pragma unroll
        for (int e = 0; e < 8; e++) gS[tid * 8 + e] = 0.f;
        gS[tid * 8 + i0] = g0;
        gS[tid * 8 + i1] = g1;
        i0S[tid] = i0; i1S[tid] = i1; g0S[tid] = g0; g1S[tid] = g1;
        topi[tid * 2] = i0; topi[tid * 2 + 1] = i1;
        topg[tid * 2] = g0; topg[tid * 2 + 1] = g1;
    }
    __syncthreads();
    for (int idx = tid; idx < 4096; idx += 256) {
        int b = idx >> 6, h = idx & 63;
        bias_y[idx] = g0S[b] * b_exp[i0S[b] * 64 + h] + g1S[b] * b_exp[i1S[b] * 64 + h];
    }
    if (tid < 64) {
        float g[8];
        #pragma unroll
        for (int e = 0; e < 8; e++) g[e] = gS[tid * 8 + e];
        float imp[8], ld[8];
        #pragma unroll
        for (int e = 0; e < 8; e++) {
            imp[e] = wsum(g[e]);
            ld[e]  = wsum(g[e] > 0.f ? 1.f : 0.f);
        }
        if (tid == 0) {
            float l = 0.f;
            {
                float s = 0.f;
                #pragma unroll
                for (int e = 0; e < 8; e++) s += imp[e];
                float mn = s / 8.f, v = 0.f;
                #pragma unroll
                for (int e = 0; e < 8; e++) { float d = imp[e] - mn; v += d * d; }
                l += (v / 7.f) / (mn * mn + 1e-10f);
            }
            {
                float s = 0.f;
                #pragma unroll
                for (int e = 0; e < 8; e++) s += ld[e];
                float mn = s / 8.f, v = 0.f;
                #pragma unroll
                for (int e = 0; e < 8; e++) { float d = ld[e] - mn; v += d * d; }
                l += (v / 7.f) / (mn * mn + 1e-10f);
            }
            loss_out[0] = 0.01f * l;
        }
    }
}

// ---------- 2. MFMA GEMMs, BK=64, conflict-free staging, register prefetch.
//   bid<512: pair=(bid>>1) rows, kind=bid&1 (0=sh f32, 1=y bf16);
//   bid>=512: kind2 rgb -> out plane. ----------
__global__ __launch_bounds__(256) void k_gemm3(const float* __restrict__ dte,
                                               const float* __restrict__ x,
                                               const float* __restrict__ W_sh,
                                               const float* __restrict__ b_sh,
                                               const float* __restrict__ W_exp,
                                               const int* __restrict__ topi,
                                               const float* __restrict__ topg,
                                               const float* __restrict__ bias_y,
                                               const float* __restrict__ W_rgb,
                                               const float* __restrict__ b_rgb,
                                               float* __restrict__ buf_sh,
                                               u16* __restrict__ buf_y,
                                               float* __restrict__ out_rgb) {
    __shared__ u16 As[64 * 72];   // A[r][k], stride 72 u16 (144 B, 16B-aligned)
    __shared__ u16 Wt[64 * 72];   // W^T[n][k], stride 72
    int bid = blockIdx.x;
    int kind, row0;
    if (bid < 512) { kind = bid & 1; row0 = (bid >> 1) * 64; }
    else           { kind = 2;       row0 = (bid - 512) * 64; }
    int b = row0 >> 8;
    int tid = threadIdx.x, wv = tid >> 6, lane = tid & 63;
    int m = lane & 15, quad = lane >> 4;

    const float* A = (kind == 2) ? x : dte;
    const float* W0 = (kind == 2) ? W_rgb : W_sh;
    const float* W1 = W0;
    float g0 = 0.f, g1 = 0.f;
    if (kind == 1) {
        W0 = W_exp + (size_t)topi[2 * b] * 49152;
        W1 = W_exp + (size_t)topi[2 * b + 1] * 49152;
        g0 = topg[2 * b]; g1 = topg[2 * b + 1];
    }

    // prefetch registers
    float4 pa[2][2];        // A: 2 chunks x 8 floats
    float  pw[16];          // W: 16 consecutive k for one n
    const int a_r  = tid >> 3;            // A chunk 0 row (chunk 1: +32)
    const int a_k8 = (tid & 7) * 8;       // k offset
    const int w_n  = tid & 63;
    const int w_k0 = (tid >> 6) * 16;

    auto loadA = [&](int kc) {
        #pragma unroll
        for (int j = 0; j < 2; j++) {
            const float* src = A + (size_t)(row0 + a_r + j * 32) * 768 + kc * 64 + a_k8;
            pa[j][0] = *(const float4*)(src);
            pa[j][1] = *(const float4*)(src + 4);
        }
    };
    auto loadW = [&](int kc) {
        if (kind == 1) {
            #pragma unroll
            for (int j = 0; j < 16; j++) {
                size_t off = (size_t)(kc * 64 + w_k0 + j) * 64 + w_n;
                pw[j] = g0 * W0[off] + g1 * W1[off];
            }
        } else {
            #pragma unroll
            for (int j = 0; j < 16; j++)
                pw[j] = W0[(size_t)(kc * 64 + w_k0 + j) * 64 + w_n];
        }
    };
    auto stageLDS = [&]() {
        #pragma unroll
        for (int j = 0; j < 2; j++) {
            uint4 d;
            d.x = pack2(pa[j][0].x, pa[j][0].y);
            d.y = pack2(pa[j][0].z, pa[j][0].w);
            d.z = pack2(pa[j][1].x, pa[j][1].y);
            d.w = pack2(pa[j][1].z, pa[j][1].w);
            *(uint4*)&As[(a_r + j * 32) * 72 + a_k8] = d;
        }
        uint4 d0, d1;
        d0.x = pack2(pw[0],  pw[1]);  d0.y = pack2(pw[2],  pw[3]);
        d0.z = pack2(pw[4],  pw[5]);  d0.w = pack2(pw[6],  pw[7]);
        d1.x = pack2(pw[8],  pw[9]);  d1.y = pack2(pw[10], pw[11]);
        d1.z = pack2(pw[12], pw[13]); d1.w = pack2(pw[14], pw[15]);
        *(uint4*)&Wt[w_n * 72 + w_k0]     = d0;
        *(uint4*)&Wt[w_n * 72 + w_k0 + 8] = d1;
    };

    f32x4 acc0 = {0.f, 0.f, 0.f, 0.f}, acc1 = acc0, acc2 = acc0, acc3 = acc0;

    loadA(0); loadW(0);
    for (int kc = 0; kc < 12; kc++) {
        __syncthreads();            // previous compute done reading LDS
        stageLDS();
        __syncthreads();            // staged data visible
        if (kc < 11) { loadA(kc + 1); loadW(kc + 1); }   // prefetch overlaps MFMAs
        const int ar = (wv * 16 + m) * 72;
        bf16x8 a0 = *(const bf16x8*)&As[ar + quad * 8];
        bf16x8 a1 = *(const bf16x8*)&As[ar + 32 + quad * 8];
        #pragma unroll
        for (int t = 0; t < 4; t++) {
            const int br = (t * 16 + m) * 72;
            bf16x8 b0 = *(const bf16x8*)&Wt[br + quad * 8];
            bf16x8 b1 = *(const bf16x8*)&Wt[br + 32 + quad * 8];
            f32x4* accp = (t == 0) ? &acc0 : (t == 1) ? &acc1 : (t == 2) ? &acc2 : &acc3;
            *accp = __builtin_amdgcn_mfma_f32_16x16x32_bf16(a0, b0, *accp, 0, 0, 0);
            *accp = __builtin_amdgcn_mfma_f32_16x16x32_bf16(a1, b1, *accp, 0, 0, 0);
        }
    }

    // epilogue: C[row0 + wv*16 + quad*4 + i][t*16 + m]
    f32x4 accs[4] = {acc0, acc1, acc2, acc3};
    #pragma unroll
    for (int t = 0; t < 4; t++) {
        int col = t * 16 + m;
        float bias;
        if (kind == 0)      bias = b_sh[col];
        else if (kind == 1) bias = bias_y[b * 64 + col];
        else                bias = b_rgb[col];
        #pragma unroll
        for (int i = 0; i < 4; i++) {
            int r = row0 + wv * 16 + quad * 4 + i;
            float val = accs[t][i] + bias;
            if (kind == 0)      buf_sh[(size_t)r * 64 + col] = val;
            else if (kind == 1) buf_y[(size_t)r * 64 + col] = f2bf(val);
            else                out_rgb[(size_t)r * 64 + col] = val;
        }
    }
}

// ---------- 3. LN + W_px -> t1, t2 (bf16); 32-row tiles, grid 512 ----------
__global__ __launch_bounds__(256) void k_lnpx(const float* __restrict__ buf_sh,
                                              const float* __restrict__ ln_g,
                                              const float* __restrict__ ln_b,
                                              const float* __restrict__ W_px,
                                              const float* __restrict__ b_px,
                                              u16* __restrict__ t1, u16* __restrict__ t2) {
    __shared__ float T[32 * 68];
    __shared__ float Wpx[8192];
    int r0 = blockIdx.x * 32;
    int tid = threadIdx.x, w = tid >> 6, lane = tid & 63;
    #pragma unroll
    for (int j = 0; j < 8; j++) {
        int e4 = tid + j * 256;
        *(float4*)(Wpx + e4 * 4) = *(const float4*)(W_px + e4 * 4);
    }
    float lnG = ln_g[lane], lnB = ln_b[lane];
    for (int i = 0; i < 8; i++) {
        int l = w * 8 + i;
        float v = buf_sh[(size_t)(r0 + l) * 64 + lane];
        float mean = wsum(v) * (1.f / 64.f);
        float d = v - mean;
        float var = wsum(d * d) * (1.f / 64.f);
        T[l * 68 + lane] = d * rsqrtf(var + 1e-6f) * lnG + lnB;
    }
    __syncthreads();
    int rg = tid >> 4, cg = tid & 15;
    float acc1[2][4] = {}, acc2[2][4] = {};
    const float* tr = T + rg * 2 * 68;
    #pragma unroll 4
    for (int kk = 0; kk < 64; kk++) {
        float a0 = tr[kk], a1 = tr[68 + kk];
        float4 w1 = *(const float4*)(Wpx + kk * 128 + cg * 4);
        float4 w2 = *(const float4*)(Wpx + kk * 128 + 64 + cg * 4);
        acc1[0][0] += a0 * w1.x; acc1[0][1] += a0 * w1.y; acc1[0][2] += a0 * w1.z; acc1[0][3] += a0 * w1.w;
        acc1[1][0] += a1 * w1.x; acc1[1][1] += a1 * w1.y; acc1[1][2] += a1 * w1.z; acc1[1][3] += a1 * w1.w;
        acc2[0][0] += a0 * w2.x; acc2[0][1] += a0 * w2.y; acc2[0][2] += a0 * w2.z; acc2[0][3] += a0 * w2.w;
        acc2[1][0] += a1 * w2.x; acc2[1][1] += a1 * w2.y; acc2[1][2] += a1 * w2.z; acc2[1][3] += a1 * w2.w;
    }
    float4 b1 = *(const float4*)(b_px + cg * 4);
    float4 b2 = *(const float4*)(b_px + 64 + cg * 4);
    #pragma unroll
    for (int i = 0; i < 2; i++) {
        int r = r0 + rg * 2 + i;
        u32* d1 = (u32*)(t1 + (size_t)r * 64 + cg * 4);
        d1[0] = pack2(acc1[i][0] + b1.x, acc1[i][1] + b1.y);
        d1[1] = pack2(acc1[i][2] + b1.z, acc1[i][3] + b1.w);
        u32* d2 = (u32*)(t2 + (size_t)r * 64 + cg * 4);
        d2[0] = pack2(acc2[i][0] + b2.x, acc2[i][1] + b2.y);
        d2[1] = pack2(acc2[i][2] + b2.z, acc2[i][3] + b2.w);
    }
}

// ---------- 4. tail; 32-row tiles, grid 512, async weight pipeline ----------
// Round-2 diagnosis: VGPR weight staging (wbuf held across phases) spilled to
// scratch -> +24 MB HBM writes (WRITE_SIZE 4->28 MB), staging serialized.
// Now: weights staged global->LDS via __builtin_amdgcn_global_load_lds
// (no VGPR roundtrip, nothing to spill). Matrix for phase p+1 issues at the
// top of phase p (which reads the OTHER ping-pong half); the end-of-phase
// __syncthreads (vmcnt(0)) guarantees visibility. 32 rows/block halves
// per-row staging traffic; grid 512 = 2 blocks/CU (LDS 72 KB).
// Per-output FMA order unchanged -> bit-identical numerics.
__global__ __launch_bounds__(256) void k_tail(const u16* __restrict__ t1,
                                              const u16* __restrict__ t2,
                                              const float* __restrict__ conv_sh,
                                              const float* __restrict__ W_pxx,
                                              const float* __restrict__ b_pxx,
                                              const float* __restrict__ buf_sh,
                                              const u16* __restrict__ buf_y,
                                              const float* __restrict__ W_dte,
                                              const float* __restrict__ b_dte,
                                              const float* __restrict__ W_dteall,
                                              const float* __restrict__ b_dteall,
                                              const float* __restrict__ W_fx,
                                              const float* __restrict__ b_fx,
                                              const float* __restrict__ W_fmod,
                                              const float* __restrict__ b_fmod,
                                              const float* __restrict__ W_fxx,
                                              const float* __restrict__ b_fxx,
                                              float* __restrict__ out) {
    __shared__ float C0[32 * 68];           // conv*t2; reused as P in phase D2
    __shared__ float GA[32 * 68];           // gelu(out residual)
    __shared__ float SH1[32 * 68];          // pxx GEMM + shortcut
    __shared__ float GM[32 * 68];           // gelu(dte_tok)
    __shared__ u16   Ybh[32 * 72];          // buf_y (bf16, raw copy)
    __shared__ __align__(16) float WL[2][4096];  // ping-pong 16 KB weight tiles
    int r0 = blockIdx.x * 32;
    int tid = threadIdx.x, w = tid >> 6, lane = tid & 63;
    int rg = tid >> 4, cg = tid & 15;

    // async global->LDS stage of one 16 KB matrix: 4 issues/wave, 1 KB each
    auto stage_w = [&](const float* __restrict__ Wsrc, int half) {
        const float* g = Wsrc + w * 1024 + lane * 4;
        float* l = &WL[half][w * 1024];
        #pragma unroll
        for (int j = 0; j < 4; j++) {
            __builtin_amdgcn_global_load_lds(
                (const __attribute__((address_space(1))) unsigned int*)(g + j * 256),
                (__attribute__((address_space(3))) unsigned int*)(l + j * 256),
                16, 0, 0);
        }
    };

    stage_w(W_pxx, 0);                      // pre-A: phase B's weights

    // ---- phase A: issue W_dte; conv, Yb copy, residual+gelu ----
    stage_w(W_dte, 1);
    float4 rsv[2];
    #pragma unroll
    for (int i = 0; i < 2; i++) {
        int r = rg * 2 + i;
        // buf_y raw bf16 copy
        uint2 v = *(const uint2*)(buf_y + (size_t)(r0 + r) * 64 + cg * 4);
        *(uint2*)(&Ybh[r * 72 + cg * 4]) = v;
        // out residual -> registers; gelu -> GA
        rsv[i] = *(const float4*)(out + (size_t)(r0 + r) * 64 + cg * 4);
        GA[r * 68 + cg * 4 + 0] = gelu_f(rsv[i].x);
        GA[r * 68 + cg * 4 + 1] = gelu_f(rsv[i].y);
        GA[r * 68 + cg * 4 + 2] = gelu_f(rsv[i].z);
        GA[r * 68 + cg * 4 + 3] = gelu_f(rsv[i].w);
    }
    {   // depthwise 3x3 conv on t1, * gelu * t2 -> C0 (8 rows/wave)
        float c0 = conv_sh[lane * 9 + 0], c1 = conv_sh[lane * 9 + 1], c2 = conv_sh[lane * 9 + 2];
        float c3 = conv_sh[lane * 9 + 3], c4 = conv_sh[lane * 9 + 4], c5 = conv_sh[lane * 9 + 5];
        float c6 = conv_sh[lane * 9 + 6], c7 = conv_sh[lane * 9 + 7], c8 = conv_sh[lane * 9 + 8];
        #pragma unroll
        for (int i = 0; i < 8; i++) {
            int l = w * 8 + i;
            int gr = r0 + l;
            int pix = gr & 255, ii = pix >> 4, jj = pix & 15;
            const u16* p = t1 + (size_t)gr * 64 + lane;
            float c = c4 * bf2f(p[0]);
            if (ii > 0) {
                c += c1 * bf2f(p[-1024]);
                if (jj > 0)  c += c0 * bf2f(p[-1024 - 64]);
                if (jj < 15) c += c2 * bf2f(p[-1024 + 64]);
            }
            if (jj > 0)  c += c3 * bf2f(p[-64]);
            if (jj < 15) c += c5 * bf2f(p[64]);
            if (ii < 15) {
                c += c7 * bf2f(p[1024]);
                if (jj > 0)  c += c6 * bf2f(p[1024 - 64]);
                if (jj < 15) c += c8 * bf2f(p[1024 + 64]);
            }
            C0[l * 68 + lane] = gelu_f(c) * bf2f(t2[(size_t)gr * 64 + lane]);
        }
    }
    __syncthreads();    // drains vmcnt(0): W_pxx (and W_dte) landed

    // ---- phase B: SH1 = C0 @ W_pxx(WL0) + b_pxx + buf_sh ----
    {
        float acc[2][4] = {};
        const float* ur = C0 + rg * 2 * 68;
        #pragma unroll 8
        for (int kk = 0; kk < 64; kk++) {
            float a0 = ur[kk], a1 = ur[68 + kk];
            float4 wv = *(const float4*)(&WL[0][kk * 64 + cg * 4]);
            acc[0][0] += a0 * wv.x; acc[0][1] += a0 * wv.y; acc[0][2] += a0 * wv.z; acc[0][3] += a0 * wv.w;
            acc[1][0] += a1 * wv.x; acc[1][1] += a1 * wv.y; acc[1][2] += a1 * wv.z; acc[1][3] += a1 * wv.w;
        }
        float4 bp = *(const float4*)(b_pxx + cg * 4);
        #pragma unroll
        for (int i = 0; i < 2; i++) {
            int r = rg * 2 + i;
            float4 shv = *(const float4*)(buf_sh + (size_t)(r0 + r) * 64 + cg * 4);
            *(float4*)(SH1 + r * 68 + cg * 4) =
                make_float4(acc[i][0] + bp.x + shv.x, acc[i][1] + bp.y + shv.y,
                            acc[i][2] + bp.z + shv.z, acc[i][3] + bp.w + shv.w);
        }
    }
    __syncthreads();

    // ---- phase C1: issue W_dteall->WL0; accC = Yb @ W_dte(WL1) ----
    float accC[2][4] = {};
    stage_w(W_dteall, 0);
    {
        const u16* yr = Ybh + rg * 2 * 72;
        #pragma unroll 8
        for (int kk = 0; kk < 64; kk++) {
            float y0 = bf2f(yr[kk]), y1 = bf2f(yr[72 + kk]);
            float4 wv = *(const float4*)(&WL[1][kk * 64 + cg * 4]);
            accC[0][0] += y0 * wv.x; accC[0][1] += y0 * wv.y; accC[0][2] += y0 * wv.z; accC[0][3] += y0 * wv.w;
            accC[1][0] += y1 * wv.x; accC[1][1] += y1 * wv.y; accC[1][2] += y1 * wv.z; accC[1][3] += y1 * wv.w;
        }
    }
    __syncthreads();

    // ---- phase C2: issue W_fx->WL1; accC += SH1 @ W_dteall(WL0); GM = gelu ----
    stage_w(W_fx, 1);
    {
        const float* sr = SH1 + rg * 2 * 68;
        #pragma unroll 8
        for (int kk = 0; kk < 64; kk++) {
            float s0 = sr[kk], s1 = sr[68 + kk];
            float4 wv = *(const float4*)(&WL[0][kk * 64 + cg * 4]);
            accC[0][0] += s0 * wv.x; accC[0][1] += s0 * wv.y; accC[0][2] += s0 * wv.z; accC[0][3] += s0 * wv.w;
            accC[1][0] += s1 * wv.x; accC[1][1] += s1 * wv.y; accC[1][2] += s1 * wv.z; accC[1][3] += s1 * wv.w;
        }
        float4 bd1 = *(const float4*)(b_dte + cg * 4);
        float4 bd2 = *(const float4*)(b_dteall + cg * 4);
        #pragma unroll
        for (int i = 0; i < 2; i++) {
            int r = rg * 2 + i;
            *(float4*)(GM + r * 68 + cg * 4) =
                make_float4(gelu_f(accC[i][0] + bd1.x + bd2.x), gelu_f(accC[i][1] + bd1.y + bd2.y),
                            gelu_f(accC[i][2] + bd1.z + bd2.z), gelu_f(accC[i][3] + bd1.w + bd2.w));
        }
    }
    __syncthreads();

    // ---- phase D1: issue W_fmod->WL0; accA = GA @ W_fx(WL1) ----
    float accA[2][4] = {};
    stage_w(W_fmod, 0);
    {
        const float* ga = GA + rg * 2 * 68;
        #pragma unroll 8
        for (int kk = 0; kk < 64; kk++) {
            float a0 = ga[kk], a1 = ga[68 + kk];
            float4 wv = *(const float4*)(&WL[1][kk * 64 + cg * 4]);
            accA[0][0] += a0 * wv.x; accA[0][1] += a0 * wv.y; accA[0][2] += a0 * wv.z; accA[0][3] += a0 * wv.w;
            accA[1][0] += a1 * wv.x; accA[1][1] += a1 * wv.y; accA[1][2] += a1 * wv.z; accA[1][3] += a1 * wv.w;
        }
    }
    __syncthreads();

    // ---- phase D2: issue W_fxx->WL1; accM = GM @ W_fmod(WL0);
    //      P(C0) = gelu(accM+bm) * (accA+bx) ----
    stage_w(W_fxx, 1);
    {
        float accM[2][4] = {};
        const float* gm = GM + rg * 2 * 68;
        #pragma unroll 8
        for (int kk = 0; kk < 64; kk++) {
            float m0 = gm[kk], m1 = gm[68 + kk];
            float4 wv = *(const float4*)(&WL[0][kk * 64 + cg * 4]);
            accM[0][0] += m0 * wv.x; accM[0][1] += m0 * wv.y; accM[0][2] += m0 * wv.z; accM[0][3] += m0 * wv.w;
            accM[1][0] += m1 * wv.x; accM[1][1] += m1 * wv.y; accM[1][2] += m1 * wv.z; accM[1][3] += m1 * wv.w;
        }
        float4 bx = *(const float4*)(b_fx + cg * 4);
        float4 bm = *(const float4*)(b_fmod + cg * 4);
        #pragma unroll
        for (int i = 0; i < 2; i++) {
            int r = rg * 2 + i;
            float a0 = accA[i][0] + bx.x, a1 = accA[i][1] + bx.y, a2 = accA[i][2] + bx.z, a3 = accA[i][3] + bx.w;
            float m0 = accM[i][0] + bm.x, m1 = accM[i][1] + bm.y, m2 = accM[i][2] + bm.z, m3 = accM[i][3] + bm.w;
            *(float4*)(C0 + r * 68 + cg * 4) =
                make_float4(gelu_f(m0) * a0, gelu_f(m1) * a1, gelu_f(m2) * a2, gelu_f(m3) * a3);
        }
    }
    __syncthreads();

    // ---- phase E: out = P(C0) @ W_fxx(WL1) + b_fxx + rsv ----
    {
        float acc[2][4] = {};
        const float* pr = C0 + rg * 2 * 68;
        #pragma unroll 8
        for (int kk = 0; kk < 64; kk++) {
            float p0 = pr[kk], p1 = pr[68 + kk];
            float4 wv = *(const float4*)(&WL[1][kk * 64 + cg * 4]);
            acc[0][0] += p0 * wv.x; acc[0][1] += p0 * wv.y; acc[0][2] += p0 * wv.z; acc[0][3] += p0 * wv.w;
            acc[1][0] += p1 * wv.x; acc[1][1] += p1 * wv.y; acc[1][2] += p1 * wv.z; acc[1][3] += p1 * wv.w;
        }
        float4 bo = *(const float4*)(b_fxx + cg * 4);
        #pragma unroll
        for (int i = 0; i < 2; i++) {
            int r = rg * 2 + i;
            *(float4*)(out + (size_t)(r0 + r) * 64 + cg * 4) =
                make_float4(acc[i][0] + bo.x + rsv[i].x, acc[i][1] + bo.y + rsv[i].y,
                            acc[i][2] + bo.z + rsv[i].z, acc[i][3] + bo.w + rsv[i].w);
        }
    }
}

extern "C" void kernel_launch(void* const* d_in, const int* in_sizes, int n_in,
                              void* d_out, int out_size, void* d_ws, size_t ws_size,
                              hipStream_t stream) {
    const float* x       = (const float*)d_in[0];
    const float* dte     = (const float*)d_in[1];
    const float* w_gate  = (const float*)d_in[2];
    const float* W_exp   = (const float*)d_in[3];
    const float* b_exp   = (const float*)d_in[4];
    const float* W_sh    = (const float*)d_in[5];
    const float* b_sh    = (const float*)d_in[6];
    const float* ln_g    = (const float*)d_in[7];
    const float* ln_b    = (const float*)d_in[8];
    const float* W_px    = (const float*)d_in[9];
    const float* b_px    = (const float*)d_in[10];
    const float* conv_sh = (const float*)d_in[11];
    const float* W_pxx   = (const float*)d_in[12];
    const float* b_pxx   = (const float*)d_in[13];
    const float* W_dte   = (const float*)d_in[14];
    const float* b_dte   = (const float*)d_in[15];
    const float* W_dteall= (const float*)d_in[16];
    const float* b_dteall= (const float*)d_in[17];
    const float* W_rgb   = (const float*)d_in[18];
    const float* b_rgb   = (const float*)d_in[19];
    const float* W_fx    = (const float*)d_in[20];
    const float* b_fx    = (const float*)d_in[21];
    const float* W_fmod  = (const float*)d_in[22];
    const float* b_fmod  = (const float*)d_in[23];
    const float* W_fxx   = (const float*)d_in[24];
    const float* b_fxx   = (const float*)d_in[25];

    float* out = (float*)d_out;     // [0,1048576) plane + loss at [1048576]

    float* wsf    = (float*)d_ws;
    float* partial= wsf;                         // 2048
    int*   topi   = (int*)(wsf + 2048);          // 128
    float* topg   = wsf + 2176;                  // 128
    float* bias_y = wsf + 2304;                  // 4096
    float* buf_sh = wsf + 8192;                  // 1048576 f32
    u16*   buf_y  = (u16*)(wsf + 8192 + 1048576);
    u16*   t1     = (u16*)(wsf + 8192 + 1048576 + 524288);
    u16*   t2     = (u16*)(wsf + 8192 + 1048576 + 524288*2);

    hipLaunchKernelGGL(k_gate_part, dim3(256), dim3(256), 0, stream, dte, w_gate, partial);
    hipLaunchKernelGGL(k_gate_fin, dim3(1), dim3(256), 0, stream,
                       partial, b_exp, topi, topg, bias_y, out + 1048576);
    hipLaunchKernelGGL(k_gemm3, dim3(768), dim3(256), 0, stream,
                       dte, x, W_sh, b_sh, W_exp, topi, topg, bias_y, W_rgb, b_rgb,
                       buf_sh, buf_y, out);
    hipLaunchKernelGGL(k_lnpx, dim3(512), dim3(256), 0, stream,
                       buf_sh, ln_g, ln_b, W_px, b_px, t1, t2);
    hipLaunchKernelGGL(k_tail, dim3(512), dim3(256), 0, stream,
                       t1, t2, conv_sh, W_pxx, b_pxx, buf_sh, buf_y,
                       W_dte, b_dte, W_dteall, b_dteall,
                       W_fx, b_fx, W_fmod, b_fmod, W_fxx, b_fxx, out);

    (void)in_sizes; (void)n_in; (void)out_size; (void)ws_size;
}

// Round 5
// 241.888 us; speedup vs baseline: 1.1056x; 1.0012x over previous
//
#include <hip/hip_runtime.h>
#include <hip/hip_bf16.h>
#include <math.h>

typedef unsigned short u16;
typedef unsigned int u32;
typedef __attribute__((ext_vector_type(8))) short bf16x8;
typedef __attribute__((ext_vector_type(4))) float f32x4;

// B=64, L=256, DIN=768, H=64, E=8, K=2, S=16; BL=16384. All inputs f32, output f32.

__device__ __forceinline__ float bf2f(u16 u) {
    union { u32 i; float f; } x; x.i = ((u32)u) << 16; return x.f;
}
// HW RNE convert (v_cvt_bf16_f32 / v_cvt_pk_bf16_f32) — same rounding as the
// old manual (i + 0x7fff + lsb)>>16 bit-twiddle, ~6x fewer VALU ops.
__device__ __forceinline__ u16 f2bf(float f) {
    union { __hip_bfloat16 h; u16 u; } x;
    x.h = __float2bfloat16(f);
    return x.u;
}
__device__ __forceinline__ u32 pack2(float a, float b) {
    union { __hip_bfloat162 h; u32 u; } x;
    x.h = __float22bfloat162_rn(make_float2(a, b));
    return x.u;
}
__device__ __forceinline__ float wsum(float v) {
    #pragma unroll
    for (int o = 1; o < 64; o <<= 1) v += __shfl_xor(v, o, 64);
    return v;
}
__device__ __forceinline__ float gelu_f(float x) {
    return 0.5f * x * (1.0f + erff(x * 0.70710678118654752440f));
}

// ---------- 1a. partial gating ----------
// Was: 16 sequential {load row -> wsum} chains per wave (un-hidden HBM latency
// at 1 block/CU). Now: load 8 rows into registers (24 loads in flight), then
// reduce. Same FP add order -> bit-identical.
__global__ __launch_bounds__(256) void k_gate_part(const float* __restrict__ dte,
                                                   const float* __restrict__ w_gate,
                                                   float* __restrict__ partial) {
    __shared__ float dmeanS[64];
    int p = blockIdx.x, tid = threadIdx.x, w = tid >> 6, lane = tid & 63;
    #pragma unroll
    for (int h = 0; h < 2; h++) {
        float4 v[8][3];
        #pragma unroll
        for (int i = 0; i < 8; i++) {
            const float* pr = dte + ((size_t)p * 64 + w * 16 + h * 8 + i) * 768;
            #pragma unroll
            for (int j = 0; j < 3; j++)
                v[i][j] = *(const float4*)(pr + (lane + j * 64) * 4);
        }
        #pragma unroll
        for (int i = 0; i < 8; i++) {
            float s = 0.f;
            #pragma unroll
            for (int j = 0; j < 3; j++)
                s += v[i][j].x + v[i][j].y + v[i][j].z + v[i][j].w;
            s = wsum(s);
            if (lane == 0) dmeanS[w * 16 + h * 8 + i] = s * (1.f / 768.f);
        }
    }
    __syncthreads();
    if (w == 0) {
        float dm = dmeanS[lane];
        int wl = (p & 3) * 64 + lane;
        #pragma unroll
        for (int e = 0; e < 8; e++) {
            float s = wsum(dm * w_gate[wl * 8 + e]);
            if (lane == 0) partial[p * 8 + e] = s;
        }
    }
}

// ---------- 1b. finalize gates + loss ----------
__global__ __launch_bounds__(256) void k_gate_fin(const float* __restrict__ partial,
                                                  const float* __restrict__ b_exp,
                                                  int* __restrict__ topi,
                                                  float* __restrict__ topg,
                                                  float* __restrict__ bias_y,
                                                  float* __restrict__ loss_out) {
    __shared__ float gS[64 * 8];
    __shared__ int i0S[64], i1S[64];
    __shared__ float g0S[64], g1S[64];
    int tid = threadIdx.x;
    if (tid < 64) {
        float lg[8];
        #pragma unroll
        for (int e = 0; e < 8; e++)
            lg[e] = partial[(tid * 4 + 0) * 8 + e] + partial[(tid * 4 + 1) * 8 + e] +
                    partial[(tid * 4 + 2) * 8 + e] + partial[(tid * 4 + 3) * 8 + e];
        int i0 = 0; float v0 = lg[0];
        #pragma unroll
        for (int e = 1; e < 8; e++) if (lg[e] > v0) { v0 = lg[e]; i0 = e; }
        int i1 = -1; float v1 = -1e30f;
        #pragma unroll
        for (int e = 0; e < 8; e++) if (e != i0 && lg[e] > v1) { v1 = lg[e]; i1 = e; }
        if (i1 < 0) i1 = (i0 + 1) & 7;
        float e2 = expf(v1 - v0);
        float g0 = 1.f / (1.f + e2);
        float g1 = e2 / (1.f + e2);
        #pragma unroll
        for (int e = 0; e < 8; e++) gS[tid * 8 + e] = 0.f;
        gS[tid * 8 + i0] = g0;
        gS[tid * 8 + i1] = g1;
        i0S[tid] = i0; i1S[tid] = i1; g0S[tid] = g0; g1S[tid] = g1;
        topi[tid * 2] = i0; topi[tid * 2 + 1] = i1;
        topg[tid * 2] = g0; topg[tid * 2 + 1] = g1;
    }
    __syncthreads();
    for (int idx = tid; idx < 4096; idx += 256) {
        int b = idx >> 6, h = idx & 63;
        bias_y[idx] = g0S[b] * b_exp[i0S[b] * 64 + h] + g1S[b] * b_exp[i1S[b] * 64 + h];
    }
    if (tid < 64) {
        float g[8];
        #pragma unroll
        for (int e = 0; e < 8; e++) g[e] = gS[tid * 8 + e];
        float imp[8], ld[8];
        #pragma unroll
        for (int e = 0; e < 8; e++) {
            imp[e] = wsum(g[e]);
            ld[e]  = wsum(g[e] > 0.f ? 1.f : 0.f);
        }
        if (tid == 0) {
            float l = 0.f;
            {
                float s = 0.f;
                #pragma unroll
                for (int e = 0; e < 8; e++) s += imp[e];
                float mn = s / 8.f, v = 0.f;
                #pragma unroll
                for (int e = 0; e < 8; e++) { float d = imp[e] - mn; v += d * d; }
                l += (v / 7.f) / (mn * mn + 1e-10f);
            }
            {
                float s = 0.f;
                #pragma unroll
                for (int e = 0; e < 8; e++) s += ld[e];
                float mn = s / 8.f, v = 0.f;
                #pragma unroll
                for (int e = 0; e < 8; e++) { float d = ld[e] - mn; v += d * d; }
                l += (v / 7.f) / (mn * mn + 1e-10f);
            }
            loss_out[0] = 0.01f * l;
        }
    }
}

// ---------- 2. MFMA GEMMs, BK=64, conflict-free staging, register prefetch.
//   bid<512: pair=(bid>>1) rows, kind=bid&1 (0=sh f32, 1=y bf16);
//   bid>=512: kind2 rgb -> out plane. pack2/f2bf now HW cvt (was the VALU
//   bottleneck: ~190 pack ops/chunk/thread -> ~16). ----------
__global__ __launch_bounds__(256) void k_gemm3(const float* __restrict__ dte,
                                               const float* __restrict__ x,
                                               const float* __restrict__ W_sh,
                                               const float* __restrict__ b_sh,
                                               const float* __restrict__ W_exp,
                                               const int* __restrict__ topi,
                                               const float* __restrict__ topg,
                                               const float* __restrict__ bias_y,
                                               const float* __restrict__ W_rgb,
                                               const float* __restrict__ b_rgb,
                                               float* __restrict__ buf_sh,
                                               u16* __restrict__ buf_y,
                                               float* __restrict__ out_rgb) {
    __shared__ u16 As[64 * 72];   // A[r][k], stride 72 u16 (144 B, 16B-aligned)
    __shared__ u16 Wt[64 * 72];   // W^T[n][k], stride 72
    int bid = blockIdx.x;
    int kind, row0;
    if (bid < 512) { kind = bid & 1; row0 = (bid >> 1) * 64; }
    else           { kind = 2;       row0 = (bid - 512) * 64; }
    int b = row0 >> 8;
    int tid = threadIdx.x, wv = tid >> 6, lane = tid & 63;
    int m = lane & 15, quad = lane >> 4;

    const float* A = (kind == 2) ? x : dte;
    const float* W0 = (kind == 2) ? W_rgb : W_sh;
    const float* W1 = W0;
    float g0 = 0.f, g1 = 0.f;
    if (kind == 1) {
        W0 = W_exp + (size_t)topi[2 * b] * 49152;
        W1 = W_exp + (size_t)topi[2 * b + 1] * 49152;
        g0 = topg[2 * b]; g1 = topg[2 * b + 1];
    }

    // prefetch registers
    float4 pa[2][2];        // A: 2 chunks x 8 floats
    float  pw[16];          // W: 16 consecutive k for one n
    const int a_r  = tid >> 3;            // A chunk 0 row (chunk 1: +32)
    const int a_k8 = (tid & 7) * 8;       // k offset
    const int w_n  = tid & 63;
    const int w_k0 = (tid >> 6) * 16;

    auto loadA = [&](int kc) {
        #pragma unroll
        for (int j = 0; j < 2; j++) {
            const float* src = A + (size_t)(row0 + a_r + j * 32) * 768 + kc * 64 + a_k8;
            pa[j][0] = *(const float4*)(src);
            pa[j][1] = *(const float4*)(src + 4);
        }
    };
    auto loadW = [&](int kc) {
        if (kind == 1) {
            #pragma unroll
            for (int j = 0; j < 16; j++) {
                size_t off = (size_t)(kc * 64 + w_k0 + j) * 64 + w_n;
                pw[j] = g0 * W0[off] + g1 * W1[off];
            }
        } else {
            #pragma unroll
            for (int j = 0; j < 16; j++)
                pw[j] = W0[(size_t)(kc * 64 + w_k0 + j) * 64 + w_n];
        }
    };
    auto stageLDS = [&]() {
        #pragma unroll
        for (int j = 0; j < 2; j++) {
            uint4 d;
            d.x = pack2(pa[j][0].x, pa[j][0].y);
            d.y = pack2(pa[j][0].z, pa[j][0].w);
            d.z = pack2(pa[j][1].x, pa[j][1].y);
            d.w = pack2(pa[j][1].z, pa[j][1].w);
            *(uint4*)&As[(a_r + j * 32) * 72 + a_k8] = d;
        }
        uint4 d0, d1;
        d0.x = pack2(pw[0],  pw[1]);  d0.y = pack2(pw[2],  pw[3]);
        d0.z = pack2(pw[4],  pw[5]);  d0.w = pack2(pw[6],  pw[7]);
        d1.x = pack2(pw[8],  pw[9]);  d1.y = pack2(pw[10], pw[11]);
        d1.z = pack2(pw[12], pw[13]); d1.w = pack2(pw[14], pw[15]);
        *(uint4*)&Wt[w_n * 72 + w_k0]     = d0;
        *(uint4*)&Wt[w_n * 72 + w_k0 + 8] = d1;
    };

    f32x4 acc0 = {0.f, 0.f, 0.f, 0.f}, acc1 = acc0, acc2 = acc0, acc3 = acc0;

    loadA(0); loadW(0);
    for (int kc = 0; kc < 12; kc++) {
        __syncthreads();            // previous compute done reading LDS
        stageLDS();
        __syncthreads();            // staged data visible
        if (kc < 11) { loadA(kc + 1); loadW(kc + 1); }   // prefetch overlaps MFMAs
        const int ar = (wv * 16 + m) * 72;
        bf16x8 a0 = *(const bf16x8*)&As[ar + quad * 8];
        bf16x8 a1 = *(const bf16x8*)&As[ar + 32 + quad * 8];
        #pragma unroll
        for (int t = 0; t < 4; t++) {
            const int br = (t * 16 + m) * 72;
            bf16x8 b0 = *(const bf16x8*)&Wt[br + quad * 8];
            bf16x8 b1 = *(const bf16x8*)&Wt[br + 32 + quad * 8];
            f32x4* accp = (t == 0) ? &acc0 : (t == 1) ? &acc1 : (t == 2) ? &acc2 : &acc3;
            *accp = __builtin_amdgcn_mfma_f32_16x16x32_bf16(a0, b0, *accp, 0, 0, 0);
            *accp = __builtin_amdgcn_mfma_f32_16x16x32_bf16(a1, b1, *accp, 0, 0, 0);
        }
    }

    // epilogue: C[row0 + wv*16 + quad*4 + i][t*16 + m]
    f32x4 accs[4] = {acc0, acc1, acc2, acc3};
    #pragma unroll
    for (int t = 0; t < 4; t++) {
        int col = t * 16 + m;
        float bias;
        if (kind == 0)      bias = b_sh[col];
        else if (kind == 1) bias = bias_y[b * 64 + col];
        else                bias = b_rgb[col];
        #pragma unroll
        for (int i = 0; i < 4; i++) {
            int r = row0 + wv * 16 + quad * 4 + i;
            float val = accs[t][i] + bias;
            if (kind == 0)      buf_sh[(size_t)r * 64 + col] = val;
            else if (kind == 1) buf_y[(size_t)r * 64 + col] = f2bf(val);
            else                out_rgb[(size_t)r * 64 + col] = val;
        }
    }
}

// ---------- 3. LN + W_px -> t1, t2 (bf16); 32-row tiles, grid 512 ----------
__global__ __launch_bounds__(256) void k_lnpx(const float* __restrict__ buf_sh,
                                              const float* __restrict__ ln_g,
                                              const float* __restrict__ ln_b,
                                              const float* __restrict__ W_px,
                                              const float* __restrict__ b_px,
                                              u16* __restrict__ t1, u16* __restrict__ t2) {
    __shared__ float T[32 * 68];
    __shared__ float Wpx[8192];
    int r0 = blockIdx.x * 32;
    int tid = threadIdx.x, w = tid >> 6, lane = tid & 63;
    #pragma unroll
    for (int j = 0; j < 8; j++) {
        int e4 = tid + j * 256;
        *(float4*)(Wpx + e4 * 4) = *(const float4*)(W_px + e4 * 4);
    }
    float lnG = ln_g[lane], lnB = ln_b[lane];
    for (int i = 0; i < 8; i++) {
        int l = w * 8 + i;
        float v = buf_sh[(size_t)(r0 + l) * 64 + lane];
        float mean = wsum(v) * (1.f / 64.f);
        float d = v - mean;
        float var = wsum(d * d) * (1.f / 64.f);
        T[l * 68 + lane] = d * rsqrtf(var + 1e-6f) * lnG + lnB;
    }
    __syncthreads();
    int rg = tid >> 4, cg = tid & 15;
    float acc1[2][4] = {}, acc2[2][4] = {};
    const float* tr = T + rg * 2 * 68;
    #pragma unroll 4
    for (int kk = 0; kk < 64; kk++) {
        float a0 = tr[kk], a1 = tr[68 + kk];
        float4 w1 = *(const float4*)(Wpx + kk * 128 + cg * 4);
        float4 w2 = *(const float4*)(Wpx + kk * 128 + 64 + cg * 4);
        acc1[0][0] += a0 * w1.x; acc1[0][1] += a0 * w1.y; acc1[0][2] += a0 * w1.z; acc1[0][3] += a0 * w1.w;
        acc1[1][0] += a1 * w1.x; acc1[1][1] += a1 * w1.y; acc1[1][2] += a1 * w1.z; acc1[1][3] += a1 * w1.w;
        acc2[0][0] += a0 * w2.x; acc2[0][1] += a0 * w2.y; acc2[0][2] += a0 * w2.z; acc2[0][3] += a0 * w2.w;
        acc2[1][0] += a1 * w2.x; acc2[1][1] += a1 * w2.y; acc2[1][2] += a1 * w2.z; acc2[1][3] += a1 * w2.w;
    }
    float4 b1 = *(const float4*)(b_px + cg * 4);
    float4 b2 = *(const float4*)(b_px + 64 + cg * 4);
    #pragma unroll
    for (int i = 0; i < 2; i++) {
        int r = r0 + rg * 2 + i;
        u32* d1 = (u32*)(t1 + (size_t)r * 64 + cg * 4);
        d1[0] = pack2(acc1[i][0] + b1.x, acc1[i][1] + b1.y);
        d1[1] = pack2(acc1[i][2] + b1.z, acc1[i][3] + b1.w);
        u32* d2 = (u32*)(t2 + (size_t)r * 64 + cg * 4);
        d2[0] = pack2(acc2[i][0] + b2.x, acc2[i][1] + b2.y);
        d2[1] = pack2(acc2[i][2] + b2.z, acc2[i][3] + b2.w);
    }
}

// ---------- 4. tail; 16-row tiles, grid 1024, async weight pipeline ----------
// Round-4 kept the async global->LDS weight pipeline (no VGPR roundtrip).
// Now 16-row tiles: with LDS-staged weights the round-1 regression mechanism
// (per-block L1 weight re-reads) is gone — doubling the grid only doubles
// L2-side staging (~98 MB aggregate, ~3 us), while LDS drops to ~51 KB ->
// 3 blocks/CU (+50% TLP in a stall-dominated kernel).
// Per-output FMA order unchanged -> bit-identical numerics.
__global__ __launch_bounds__(256) void k_tail(const u16* __restrict__ t1,
                                              const u16* __restrict__ t2,
                                              const float* __restrict__ conv_sh,
                                              const float* __restrict__ W_pxx,
                                              const float* __restrict__ b_pxx,
                                              const float* __restrict__ buf_sh,
                                              const u16* __restrict__ buf_y,
                                              const float* __restrict__ W_dte,
                                              const float* __restrict__ b_dte,
                                              const float* __restrict__ W_dteall,
                                              const float* __restrict__ b_dteall,
                                              const float* __restrict__ W_fx,
                                              const float* __restrict__ b_fx,
                                              const float* __restrict__ W_fmod,
                                              const float* __restrict__ b_fmod,
                                              const float* __restrict__ W_fxx,
                                              const float* __restrict__ b_fxx,
                                              float* __restrict__ out) {
    __shared__ float C0[16 * 68];           // conv*t2; reused as P in phase D2
    __shared__ float GA[16 * 68];           // gelu(out residual)
    __shared__ float SH1[16 * 68];          // pxx GEMM + shortcut
    __shared__ float GM[16 * 68];           // gelu(dte_tok)
    __shared__ u16   Ybh[16 * 72];          // buf_y (bf16, raw copy)
    __shared__ __align__(16) float WL[2][4096];  // ping-pong 16 KB weight tiles
    int r0 = blockIdx.x * 16;
    int tid = threadIdx.x, w = tid >> 6, lane = tid & 63;
    int rg = tid >> 4, cg = tid & 15;

    // async global->LDS stage of one 16 KB matrix: 4 issues/wave, 1 KB each
    auto stage_w = [&](const float* __restrict__ Wsrc, int half) {
        const float* g = Wsrc + w * 1024 + lane * 4;
        float* l = &WL[half][w * 1024];
        #pragma unroll
        for (int j = 0; j < 4; j++) {
            __builtin_amdgcn_global_load_lds(
                (const __attribute__((address_space(1))) unsigned int*)(g + j * 256),
                (__attribute__((address_space(3))) unsigned int*)(l + j * 256),
                16, 0, 0);
        }
    };

    stage_w(W_pxx, 0);                      // pre-A: phase B's weights

    // ---- phase A: issue W_dte; conv, Yb copy, residual+gelu ----
    stage_w(W_dte, 1);
    float4 rsv;
    {
        // buf_y raw bf16 copy (one row per 16-thread group)
        uint2 v = *(const uint2*)(buf_y + (size_t)(r0 + rg) * 64 + cg * 4);
        *(uint2*)(&Ybh[rg * 72 + cg * 4]) = v;
        // out residual -> registers; gelu -> GA
        rsv = *(const float4*)(out + (size_t)(r0 + rg) * 64 + cg * 4);
        GA[rg * 68 + cg * 4 + 0] = gelu_f(rsv.x);
        GA[rg * 68 + cg * 4 + 1] = gelu_f(rsv.y);
        GA[rg * 68 + cg * 4 + 2] = gelu_f(rsv.z);
        GA[rg * 68 + cg * 4 + 3] = gelu_f(rsv.w);
    }
    {   // depthwise 3x3 conv on t1, * gelu * t2 -> C0 (4 rows/wave)
        float c0 = conv_sh[lane * 9 + 0], c1 = conv_sh[lane * 9 + 1], c2 = conv_sh[lane * 9 + 2];
        float c3 = conv_sh[lane * 9 + 3], c4 = conv_sh[lane * 9 + 4], c5 = conv_sh[lane * 9 + 5];
        float c6 = conv_sh[lane * 9 + 6], c7 = conv_sh[lane * 9 + 7], c8 = conv_sh[lane * 9 + 8];
        #pragma unroll
        for (int i = 0; i < 4; i++) {
            int l = w * 4 + i;
            int gr = r0 + l;
            int pix = gr & 255, ii = pix >> 4, jj = pix & 15;
            const u16* p = t1 + (size_t)gr * 64 + lane;
            float c = c4 * bf2f(p[0]);
            if (ii > 0) {
                c += c1 * bf2f(p[-1024]);
                if (jj > 0)  c += c0 * bf2f(p[-1024 - 64]);
                if (jj < 15) c += c2 * bf2f(p[-1024 + 64]);
            }
            if (jj > 0)  c += c3 * bf2f(p[-64]);
            if (jj < 15) c += c5 * bf2f(p[64]);
            if (ii < 15) {
                c += c7 * bf2f(p[1024]);
                if (jj > 0)  c += c6 * bf2f(p[1024 - 64]);
                if (jj < 15) c += c8 * bf2f(p[1024 + 64]);
            }
            C0[l * 68 + lane] = gelu_f(c) * bf2f(t2[(size_t)gr * 64 + lane]);
        }
    }
    __syncthreads();    // drains vmcnt(0): W_pxx (and W_dte) landed

    // ---- phase B: SH1 = C0 @ W_pxx(WL0) + b_pxx + buf_sh ----
    {
        float acc[4] = {};
        const float* ur = C0 + rg * 68;
        #pragma unroll 8
        for (int kk = 0; kk < 64; kk++) {
            float a0 = ur[kk];
            float4 wv = *(const float4*)(&WL[0][kk * 64 + cg * 4]);
            acc[0] += a0 * wv.x; acc[1] += a0 * wv.y; acc[2] += a0 * wv.z; acc[3] += a0 * wv.w;
        }
        float4 bp = *(const float4*)(b_pxx + cg * 4);
        float4 shv = *(const float4*)(buf_sh + (size_t)(r0 + rg) * 64 + cg * 4);
        *(float4*)(SH1 + rg * 68 + cg * 4) =
            make_float4(acc[0] + bp.x + shv.x, acc[1] + bp.y + shv.y,
                        acc[2] + bp.z + shv.z, acc[3] + bp.w + shv.w);
    }
    __syncthreads();

    // ---- phase C1: issue W_dteall->WL0; accC = Yb @ W_dte(WL1) ----
    float accC[4] = {};
    stage_w(W_dteall, 0);
    {
        const u16* yr = Ybh + rg * 72;
        #pragma unroll 8
        for (int kk = 0; kk < 64; kk++) {
            float y0 = bf2f(yr[kk]);
            float4 wv = *(const float4*)(&WL[1][kk * 64 + cg * 4]);
            accC[0] += y0 * wv.x; accC[1] += y0 * wv.y; accC[2] += y0 * wv.z; accC[3] += y0 * wv.w;
        }
    }
    __syncthreads();

    // ---- phase C2: issue W_fx->WL1; accC += SH1 @ W_dteall(WL0); GM = gelu ----
    stage_w(W_fx, 1);
    {
        const float* sr = SH1 + rg * 68;
        #pragma unroll 8
        for (int kk = 0; kk < 64; kk++) {
            float s0 = sr[kk];
            float4 wv = *(const float4*)(&WL[0][kk * 64 + cg * 4]);
            accC[0] += s0 * wv.x; accC[1] += s0 * wv.y; accC[2] += s0 * wv.z; accC[3] += s0 * wv.w;
        }
        float4 bd1 = *(const float4*)(b_dte + cg * 4);
        float4 bd2 = *(const float4*)(b_dteall + cg * 4);
        *(float4*)(GM + rg * 68 + cg * 4) =
            make_float4(gelu_f(accC[0] + bd1.x + bd2.x), gelu_f(accC[1] + bd1.y + bd2.y),
                        gelu_f(accC[2] + bd1.z + bd2.z), gelu_f(accC[3] + bd1.w + bd2.w));
    }
    __syncthreads();

    // ---- phase D1: issue W_fmod->WL0; accA = GA @ W_fx(WL1) ----
    float accA[4] = {};
    stage_w(W_fmod, 0);
    {
        const float* ga = GA + rg * 68;
        #pragma unroll 8
        for (int kk = 0; kk < 64; kk++) {
            float a0 = ga[kk];
            float4 wv = *(const float4*)(&WL[1][kk * 64 + cg * 4]);
            accA[0] += a0 * wv.x; accA[1] += a0 * wv.y; accA[2] += a0 * wv.z; accA[3] += a0 * wv.w;
        }
    }
    __syncthreads();

    // ---- phase D2: issue W_fxx->WL1; accM = GM @ W_fmod(WL0);
    //      P(C0) = gelu(accM+bm) * (accA+bx) ----
    stage_w(W_fxx, 1);
    {
        float accM[4] = {};
        const float* gm = GM + rg * 68;
        #pragma unroll 8
        for (int kk = 0; kk < 64; kk++) {
            float m0 = gm[kk];
            float4 wv = *(const float4*)(&WL[0][kk * 64 + cg * 4]);
            accM[0] += m0 * wv.x; accM[1] += m0 * wv.y; accM[2] += m0 * wv.z; accM[3] += m0 * wv.w;
        }
        float4 bx = *(const float4*)(b_fx + cg * 4);
        float4 bm = *(const float4*)(b_fmod + cg * 4);
        float a0 = accA[0] + bx.x, a1 = accA[1] + bx.y, a2 = accA[2] + bx.z, a3 = accA[3] + bx.w;
        float m0 = accM[0] + bm.x, m1 = accM[1] + bm.y, m2 = accM[2] + bm.z, m3 = accM[3] + bm.w;
        *(float4*)(C0 + rg * 68 + cg * 4) =
            make_float4(gelu_f(m0) * a0, gelu_f(m1) * a1, gelu_f(m2) * a2, gelu_f(m3) * a3);
    }
    __syncthreads();

    // ---- phase E: out = P(C0) @ W_fxx(WL1) + b_fxx + rsv ----
    {
        float acc[4] = {};
        const float* pr = C0 + rg * 68;
        #pragma unroll 8
        for (int kk = 0; kk < 64; kk++) {
            float p0 = pr[kk];
            float4 wv = *(const float4*)(&WL[1][kk * 64 + cg * 4]);
            acc[0] += p0 * wv.x; acc[1] += p0 * wv.y; acc[2] += p0 * wv.z; acc[3] += p0 * wv.w;
        }
        float4 bo = *(const float4*)(b_fxx + cg * 4);
        *(float4*)(out + (size_t)(r0 + rg) * 64 + cg * 4) =
            make_float4(acc[0] + bo.x + rsv.x, acc[1] + bo.y + rsv.y,
                        acc[2] + bo.z + rsv.z, acc[3] + bo.w + rsv.w);
    }
}

extern "C" void kernel_launch(void* const* d_in, const int* in_sizes, int n_in,
                              void* d_out, int out_size, void* d_ws, size_t ws_size,
                              hipStream_t stream) {
    const float* x       = (const float*)d_in[0];
    const float* dte     = (const float*)d_in[1];
    const float* w_gate  = (const float*)d_in[2];
    const float* W_exp   = (const float*)d_in[3];
    const float* b_exp   = (const float*)d_in[4];
    const float* W_sh    = (const float*)d_in[5];
    const float* b_sh    = (const float*)d_in[6];
    const float* ln_g    = (const float*)d_in[7];
    const float* ln_b    = (const float*)d_in[8];
    const float* W_px    = (const float*)d_in[9];
    const float* b_px    = (const float*)d_in[10];
    const float* conv_sh = (const float*)d_in[11];
    const float* W_pxx   = (const float*)d_in[12];
    const float* b_pxx   = (const float*)d_in[13];
    const float* W_dte   = (const float*)d_in[14];
    const float* b_dte   = (const float*)d_in[15];
    const float* W_dteall= (const float*)d_in[16];
    const float* b_dteall= (const float*)d_in[17];
    const float* W_rgb   = (const float*)d_in[18];
    const float* b_rgb   = (const float*)d_in[19];
    const float* W_fx    = (const float*)d_in[20];
    const float* b_fx    = (const float*)d_in[21];
    const float* W_fmod  = (const float*)d_in[22];
    const float* b_fmod  = (const float*)d_in[23];
    const float* W_fxx   = (const float*)d_in[24];
    const float* b_fxx   = (const float*)d_in[25];

    float* out = (float*)d_out;     // [0,1048576) plane + loss at [1048576]

    float* wsf    = (float*)d_ws;
    float* partial= wsf;                         // 2048
    int*   topi   = (int*)(wsf + 2048);          // 128
    float* topg   = wsf + 2176;                  // 128
    float* bias_y = wsf + 2304;                  // 4096
    float* buf_sh = wsf + 8192;                  // 1048576 f32
    u16*   buf_y  = (u16*)(wsf + 8192 + 1048576);
    u16*   t1     = (u16*)(wsf + 8192 + 1048576 + 524288);
    u16*   t2     = (u16*)(wsf + 8192 + 1048576 + 524288*2);

    hipLaunchKernelGGL(k_gate_part, dim3(256), dim3(256), 0, stream, dte, w_gate, partial);
    hipLaunchKernelGGL(k_gate_fin, dim3(1), dim3(256), 0, stream,
                       partial, b_exp, topi, topg, bias_y, out + 1048576);
    hipLaunchKernelGGL(k_gemm3, dim3(768), dim3(256), 0, stream,
                       dte, x, W_sh, b_sh, W_exp, topi, topg, bias_y, W_rgb, b_rgb,
                       buf_sh, buf_y, out);
    hipLaunchKernelGGL(k_lnpx, dim3(512), dim3(256), 0, stream,
                       buf_sh, ln_g, ln_b, W_px, b_px, t1, t2);
    hipLaunchKernelGGL(k_tail, dim3(1024), dim3(256), 0, stream,
                       t1, t2, conv_sh, W_pxx, b_pxx, buf_sh, buf_y,
                       W_dte, b_dte, W_dteall, b_dteall,
                       W_fx, b_fx, W_fmod, b_fmod, W_fxx, b_fxx, out);

    (void)in_sizes; (void)n_in; (void)out_size; (void)ws_size;
}

// Round 7
// 235.727 us; speedup vs baseline: 1.1345x; 1.0261x over previous
//
#include <hip/hip_runtime.h>
#include <hip/hip_bf16.h>
#include <math.h>

typedef unsigned short u16;
typedef unsigned int u32;
typedef __attribute__((ext_vector_type(8))) short bf16x8;
typedef __attribute__((ext_vector_type(4))) float f32x4;

// B=64, L=256, DIN=768, H=64, E=8, K=2, S=16; BL=16384. All inputs f32, output f32.

__device__ __forceinline__ float bf2f(u16 u) {
    union { u32 i; float f; } x; x.i = ((u32)u) << 16; return x.f;
}
// HW RNE convert — same rounding as manual (i + 0x7fff + lsb)>>16 bit-twiddle.
__device__ __forceinline__ u16 f2bf(float f) {
    union { __hip_bfloat16 h; u16 u; } x;
    x.h = __float2bfloat16(f);
    return x.u;
}
__device__ __forceinline__ u32 pack2(float a, float b) {
    union { __hip_bfloat162 h; u32 u; } x;
    x.h = __float22bfloat162_rn(make_float2(a, b));
    return x.u;
}
__device__ __forceinline__ float wsum(float v) {
    #pragma unroll
    for (int o = 1; o < 64; o <<= 1) v += __shfl_xor(v, o, 64);
    return v;
}
__device__ __forceinline__ float gelu_f(float x) {
    return 0.5f * x * (1.0f + erff(x * 0.70710678118654752440f));
}

// ---------- 1a. partial gating (batched loads) ----------
__global__ __launch_bounds__(256) void k_gate_part(const float* __restrict__ dte,
                                                   const float* __restrict__ w_gate,
                                                   float* __restrict__ partial) {
    __shared__ float dmeanS[64];
    int p = blockIdx.x, tid = threadIdx.x, w = tid >> 6, lane = tid & 63;
    #pragma unroll
    for (int h = 0; h < 2; h++) {
        float4 v[8][3];
        #pragma unroll
        for (int i = 0; i < 8; i++) {
            const float* pr = dte + ((size_t)p * 64 + w * 16 + h * 8 + i) * 768;
            #pragma unroll
            for (int j = 0; j < 3; j++)
                v[i][j] = *(const float4*)(pr + (lane + j * 64) * 4);
        }
        #pragma unroll
        for (int i = 0; i < 8; i++) {
            float s = 0.f;
            #pragma unroll
            for (int j = 0; j < 3; j++)
                s += v[i][j].x + v[i][j].y + v[i][j].z + v[i][j].w;
            s = wsum(s);
            if (lane == 0) dmeanS[w * 16 + h * 8 + i] = s * (1.f / 768.f);
        }
    }
    __syncthreads();
    if (w == 0) {
        float dm = dmeanS[lane];
        int wl = (p & 3) * 64 + lane;
        #pragma unroll
        for (int e = 0; e < 8; e++) {
            float s = wsum(dm * w_gate[wl * 8 + e]);
            if (lane == 0) partial[p * 8 + e] = s;
        }
    }
}

// ---------- 1b. finalize gates + loss ----------
__global__ __launch_bounds__(256) void k_gate_fin(const float* __restrict__ partial,
                                                  const float* __restrict__ b_exp,
                                                  int* __restrict__ topi,
                                                  float* __restrict__ topg,
                                                  float* __restrict__ bias_y,
                                                  float* __restrict__ loss_out) {
    __shared__ float gS[64 * 8];
    __shared__ int i0S[64], i1S[64];
    __shared__ float g0S[64], g1S[64];
    int tid = threadIdx.x;
    if (tid < 64) {
        float lg[8];
        #pragma unroll
        for (int e = 0; e < 8; e++)
            lg[e] = partial[(tid * 4 + 0) * 8 + e] + partial[(tid * 4 + 1) * 8 + e] +
                    partial[(tid * 4 + 2) * 8 + e] + partial[(tid * 4 + 3) * 8 + e];
        int i0 = 0; float v0 = lg[0];
        #pragma unroll
        for (int e = 1; e < 8; e++) if (lg[e] > v0) { v0 = lg[e]; i0 = e; }
        int i1 = -1; float v1 = -1e30f;
        #pragma unroll
        for (int e = 0; e < 8; e++) if (e != i0 && lg[e] > v1) { v1 = lg[e]; i1 = e; }
        if (i1 < 0) i1 = (i0 + 1) & 7;
        float e2 = expf(v1 - v0);
        float g0 = 1.f / (1.f + e2);
        float g1 = e2 / (1.f + e2);
        #pragma unroll
        for (int e = 0; e < 8; e++) gS[tid * 8 + e] = 0.f;
        gS[tid * 8 + i0] = g0;
        gS[tid * 8 + i1] = g1;
        i0S[tid] = i0; i1S[tid] = i1; g0S[tid] = g0; g1S[tid] = g1;
        topi[tid * 2] = i0; topi[tid * 2 + 1] = i1;
        topg[tid * 2] = g0; topg[tid * 2 + 1] = g1;
    }
    __syncthreads();
    for (int idx = tid; idx < 4096; idx += 256) {
        int b = idx >> 6, h = idx & 63;
        bias_y[idx] = g0S[b] * b_exp[i0S[b] * 64 + h] + g1S[b] * b_exp[i1S[b] * 64 + h];
    }
    if (tid < 64) {
        float g[8];
        #pragma unroll
        for (int e = 0; e < 8; e++) g[e] = gS[tid * 8 + e];
        float imp[8], ld[8];
        #pragma unroll
        for (int e = 0; e < 8; e++) {
            imp[e] = wsum(g[e]);
            ld[e]  = wsum(g[e] > 0.f ? 1.f : 0.f);
        }
        if (tid == 0) {
            float l = 0.f;
            {
                float s = 0.f;
                #pragma unroll
                for (int e = 0; e < 8; e++) s += imp[e];
                float mn = s / 8.f, v = 0.f;
                #pragma unroll
                for (int e = 0; e < 8; e++) { float d = imp[e] - mn; v += d * d; }
                l += (v / 7.f) / (mn * mn + 1e-10f);
            }
            {
                float s = 0.f;
                #pragma unroll
                for (int e = 0; e < 8; e++) s += ld[e];
                float mn = s / 8.f, v = 0.f;
                #pragma unroll
                for (int e = 0; e < 8; e++) { float d = ld[e] - mn; v += d * d; }
                l += (v / 7.f) / (mn * mn + 1e-10f);
            }
            loss_out[0] = 0.01f * l;
        }
    }
}

// ---------- 2. MFMA GEMMs, BK=64. FUSED: bid<256 computes BOTH sh (W_sh)
// and y (expert-mix) GEMMs from ONE A-staging (was 2 blocks re-reading +
// re-packing the same dte rows, often on different XCDs -> 48 MB extra HBM).
// bid>=256: rgb -> out plane. Per-accumulator MFMA order unchanged ->
// bit-identical outputs. ----------
__global__ __launch_bounds__(256) void k_gemm3(const float* __restrict__ dte,
                                               const float* __restrict__ x,
                                               const float* __restrict__ W_sh,
                                               const float* __restrict__ b_sh,
                                               const float* __restrict__ W_exp,
                                               const int* __restrict__ topi,
                                               const float* __restrict__ topg,
                                               const float* __restrict__ bias_y,
                                               const float* __restrict__ W_rgb,
                                               const float* __restrict__ b_rgb,
                                               float* __restrict__ buf_sh,
                                               u16* __restrict__ buf_y,
                                               float* __restrict__ out_rgb) {
    __shared__ __align__(16) u16 As[64 * 72];    // A[r][k], stride 72 u16
    __shared__ __align__(16) u16 Wt0[64 * 72];   // W_sh^T or W_rgb^T [n][k]
    __shared__ __align__(16) u16 Wt1[64 * 72];   // expert mix ^T (fused only)
    int bid = blockIdx.x;
    bool fused = bid < 256;
    int row0 = fused ? bid * 64 : (bid - 256) * 64;
    int b = row0 >> 8;
    int tid = threadIdx.x, wv = tid >> 6, lane = tid & 63;
    int m = lane & 15, quad = lane >> 4;

    const float* A  = fused ? dte : x;
    const float* Wb = fused ? W_sh : W_rgb;
    const float* We0 = W_exp;
    const float* We1 = W_exp;
    float g0 = 0.f, g1 = 0.f;
    if (fused) {
        We0 = W_exp + (size_t)topi[2 * b] * 49152;
        We1 = W_exp + (size_t)topi[2 * b + 1] * 49152;
        g0 = topg[2 * b]; g1 = topg[2 * b + 1];
    }

    // prefetch registers
    float4 pa[2][2];        // A: 2 chunks x 8 floats
    float  pw0[16];         // base weight: 16 consecutive k for one n
    float  pw1[16];         // expert mix (fused only)
    const int a_r  = tid >> 3;            // A chunk 0 row (chunk 1: +32)
    const int a_k8 = (tid & 7) * 8;       // k offset
    const int w_n  = tid & 63;
    const int w_k0 = (tid >> 6) * 16;

    auto loadA = [&](int kc) {
        #pragma unroll
        for (int j = 0; j < 2; j++) {
            const float* src = A + (size_t)(row0 + a_r + j * 32) * 768 + kc * 64 + a_k8;
            pa[j][0] = *(const float4*)(src);
            pa[j][1] = *(const float4*)(src + 4);
        }
    };
    auto loadW = [&](int kc) {
        #pragma unroll
        for (int j = 0; j < 16; j++)
            pw0[j] = Wb[(size_t)(kc * 64 + w_k0 + j) * 64 + w_n];
        if (fused) {
            #pragma unroll
            for (int j = 0; j < 16; j++) {
                size_t off = (size_t)(kc * 64 + w_k0 + j) * 64 + w_n;
                pw1[j] = g0 * We0[off] + g1 * We1[off];
            }
        }
    };
    auto stageLDS = [&]() {
        #pragma unroll
        for (int j = 0; j < 2; j++) {
            uint4 d;
            d.x = pack2(pa[j][0].x, pa[j][0].y);
            d.y = pack2(pa[j][0].z, pa[j][0].w);
            d.z = pack2(pa[j][1].x, pa[j][1].y);
            d.w = pack2(pa[j][1].z, pa[j][1].w);
            *(uint4*)&As[(a_r + j * 32) * 72 + a_k8] = d;
        }
        {
            uint4 d0, d1;
            d0.x = pack2(pw0[0],  pw0[1]);  d0.y = pack2(pw0[2],  pw0[3]);
            d0.z = pack2(pw0[4],  pw0[5]);  d0.w = pack2(pw0[6],  pw0[7]);
            d1.x = pack2(pw0[8],  pw0[9]);  d1.y = pack2(pw0[10], pw0[11]);
            d1.z = pack2(pw0[12], pw0[13]); d1.w = pack2(pw0[14], pw0[15]);
            *(uint4*)&Wt0[w_n * 72 + w_k0]     = d0;
            *(uint4*)&Wt0[w_n * 72 + w_k0 + 8] = d1;
        }
        if (fused) {
            uint4 d0, d1;
            d0.x = pack2(pw1[0],  pw1[1]);  d0.y = pack2(pw1[2],  pw1[3]);
            d0.z = pack2(pw1[4],  pw1[5]);  d0.w = pack2(pw1[6],  pw1[7]);
            d1.x = pack2(pw1[8],  pw1[9]);  d1.y = pack2(pw1[10], pw1[11]);
            d1.z = pack2(pw1[12], pw1[13]); d1.w = pack2(pw1[14], pw1[15]);
            *(uint4*)&Wt1[w_n * 72 + w_k0]     = d0;
            *(uint4*)&Wt1[w_n * 72 + w_k0 + 8] = d1;
        }
    };

    f32x4 z = {0.f, 0.f, 0.f, 0.f};
    f32x4 s0 = z, s1 = z, s2 = z, s3 = z;      // GEMM0 (sh / rgb)
    f32x4 y0 = z, y1 = z, y2 = z, y3 = z;      // GEMM1 (y, fused only)

    loadA(0); loadW(0);
    for (int kc = 0; kc < 12; kc++) {
        __syncthreads();            // previous compute done reading LDS
        stageLDS();
        __syncthreads();            // staged data visible
        if (kc < 11) { loadA(kc + 1); loadW(kc + 1); }   // prefetch overlaps MFMAs
        const int ar = (wv * 16 + m) * 72;
        bf16x8 a0 = *(const bf16x8*)&As[ar + quad * 8];
        bf16x8 a1 = *(const bf16x8*)&As[ar + 32 + quad * 8];
        #pragma unroll
        for (int t = 0; t < 4; t++) {
            const int br = (t * 16 + m) * 72;
            bf16x8 b0 = *(const bf16x8*)&Wt0[br + quad * 8];
            bf16x8 b1 = *(const bf16x8*)&Wt0[br + 32 + quad * 8];
            f32x4* sp = (t == 0) ? &s0 : (t == 1) ? &s1 : (t == 2) ? &s2 : &s3;
            *sp = __builtin_amdgcn_mfma_f32_16x16x32_bf16(a0, b0, *sp, 0, 0, 0);
            *sp = __builtin_amdgcn_mfma_f32_16x16x32_bf16(a1, b1, *sp, 0, 0, 0);
            if (fused) {
                bf16x8 c0 = *(const bf16x8*)&Wt1[br + quad * 8];
                bf16x8 c1 = *(const bf16x8*)&Wt1[br + 32 + quad * 8];
                f32x4* yp = (t == 0) ? &y0 : (t == 1) ? &y1 : (t == 2) ? &y2 : &y3;
                *yp = __builtin_amdgcn_mfma_f32_16x16x32_bf16(a0, c0, *yp, 0, 0, 0);
                *yp = __builtin_amdgcn_mfma_f32_16x16x32_bf16(a1, c1, *yp, 0, 0, 0);
            }
        }
    }

    // epilogue: C[row0 + wv*16 + quad*4 + i][t*16 + m]
    f32x4 accs0[4] = {s0, s1, s2, s3};
    f32x4 accs1[4] = {y0, y1, y2, y3};
    #pragma unroll
    for (int t = 0; t < 4; t++) {
        int col = t * 16 + m;
        if (fused) {
            float bs = b_sh[col];
            float by = bias_y[b * 64 + col];
            #pragma unroll
            for (int i = 0; i < 4; i++) {
                int r = row0 + wv * 16 + quad * 4 + i;
                buf_sh[(size_t)r * 64 + col] = accs0[t][i] + bs;
                buf_y[(size_t)r * 64 + col]  = f2bf(accs1[t][i] + by);
            }
        } else {
            float br = b_rgb[col];
            #pragma unroll
            for (int i = 0; i < 4; i++) {
                int r = row0 + wv * 16 + quad * 4 + i;
                out_rgb[(size_t)r * 64 + col] = accs0[t][i] + br;
            }
        }
    }
}

// ---------- 3. LN + W_px -> t1, t2 (bf16); 32-row tiles, grid 512.
// Wpx staged async global->LDS (no VGPR roundtrip); LN compute overlaps
// the DMA; the pre-GEMM __syncthreads drains vmcnt. Bit-identical. ----------
__global__ __launch_bounds__(256) void k_lnpx(const float* __restrict__ buf_sh,
                                              const float* __restrict__ ln_g,
                                              const float* __restrict__ ln_b,
                                              const float* __restrict__ W_px,
                                              const float* __restrict__ b_px,
                                              u16* __restrict__ t1, u16* __restrict__ t2) {
    __shared__ float T[32 * 68];
    __shared__ __align__(16) float Wpx[8192];
    int r0 = blockIdx.x * 32;
    int tid = threadIdx.x, w = tid >> 6, lane = tid & 63;
    #pragma unroll
    for (int j = 0; j < 8; j++) {
        const float* g = W_px + (size_t)(w * 64 + j * 256) * 4 + lane * 4;
        float* l = Wpx + (w * 64 + j * 256) * 4;
        __builtin_amdgcn_global_load_lds(
            (const __attribute__((address_space(1))) unsigned int*)g,
            (__attribute__((address_space(3))) unsigned int*)l,
            16, 0, 0);
    }
    float lnG = ln_g[lane], lnB = ln_b[lane];
    for (int i = 0; i < 8; i++) {
        int l = w * 8 + i;
        float v = buf_sh[(size_t)(r0 + l) * 64 + lane];
        float mean = wsum(v) * (1.f / 64.f);
        float d = v - mean;
        float var = wsum(d * d) * (1.f / 64.f);
        T[l * 68 + lane] = d * rsqrtf(var + 1e-6f) * lnG + lnB;
    }
    __syncthreads();    // drains vmcnt: Wpx landed
    int rg = tid >> 4, cg = tid & 15;
    float acc1[2][4] = {}, acc2[2][4] = {};
    const float* tr = T + rg * 2 * 68;
    #pragma unroll 4
    for (int kk = 0; kk < 64; kk++) {
        float a0 = tr[kk], a1 = tr[68 + kk];
        float4 w1 = *(const float4*)(Wpx + kk * 128 + cg * 4);
        float4 w2 = *(const float4*)(Wpx + kk * 128 + 64 + cg * 4);
        acc1[0][0] += a0 * w1.x; acc1[0][1] += a0 * w1.y; acc1[0][2] += a0 * w1.z; acc1[0][3] += a0 * w1.w;
        acc1[1][0] += a1 * w1.x; acc1[1][1] += a1 * w1.y; acc1[1][2] += a1 * w1.z; acc1[1][3] += a1 * w1.w;
        acc2[0][0] += a0 * w2.x; acc2[0][1] += a0 * w2.y; acc2[0][2] += a0 * w2.z; acc2[0][3] += a0 * w2.w;
        acc2[1][0] += a1 * w2.x; acc2[1][1] += a1 * w2.y; acc2[1][2] += a1 * w2.z; acc2[1][3] += a1 * w2.w;
    }
    float4 b1 = *(const float4*)(b_px + cg * 4);
    float4 b2 = *(const float4*)(b_px + 64 + cg * 4);
    #pragma unroll
    for (int i = 0; i < 2; i++) {
        int r = r0 + rg * 2 + i;
        u32* d1 = (u32*)(t1 + (size_t)r * 64 + cg * 4);
        d1[0] = pack2(acc1[i][0] + b1.x, acc1[i][1] + b1.y);
        d1[1] = pack2(acc1[i][2] + b1.z, acc1[i][3] + b1.w);
        u32* d2 = (u32*)(t2 + (size_t)r * 64 + cg * 4);
        d2[0] = pack2(acc2[i][0] + b2.x, acc2[i][1] + b2.y);
        d2[1] = pack2(acc2[i][2] + b2.z, acc2[i][3] + b2.w);
    }
}

// ---------- 4. tail; 32-row tiles, grid 512, async weight pipeline ----------
// (round-4 config: 2 rows/thread halves LDS weight traffic vs the 16-row
//  variant — tail GEMM phases are LDS-BW-bound on weight re-reads.)
__global__ __launch_bounds__(256) void k_tail(const u16* __restrict__ t1,
                                              const u16* __restrict__ t2,
                                              const float* __restrict__ conv_sh,
                                              const float* __restrict__ W_pxx,
                                              const float* __restrict__ b_pxx,
                                              const float* __restrict__ buf_sh,
                                              const u16* __restrict__ buf_y,
                                              const float* __restrict__ W_dte,
                                              const float* __restrict__ b_dte,
                                              const float* __restrict__ W_dteall,
                                              const float* __restrict__ b_dteall,
                                              const float* __restrict__ W_fx,
                                              const float* __restrict__ b_fx,
                                              const float* __restrict__ W_fmod,
                                              const float* __restrict__ b_fmod,
                                              const float* __restrict__ W_fxx,
                                              const float* __restrict__ b_fxx,
                                              float* __restrict__ out) {
    __shared__ float C0[32 * 68];           // conv*t2; reused as P in phase D2
    __shared__ float GA[32 * 68];           // gelu(out residual)
    __shared__ float SH1[32 * 68];          // pxx GEMM + shortcut
    __shared__ float GM[32 * 68];           // gelu(dte_tok)
    __shared__ u16   Ybh[32 * 72];          // buf_y (bf16, raw copy)
    __shared__ __align__(16) float WL[2][4096];  // ping-pong 16 KB weight tiles
    int r0 = blockIdx.x * 32;
    int tid = threadIdx.x, w = tid >> 6, lane = tid & 63;
    int rg = tid >> 4, cg = tid & 15;

    // async global->LDS stage of one 16 KB matrix: 4 issues/wave, 1 KB each
    auto stage_w = [&](const float* __restrict__ Wsrc, int half) {
        const float* g = Wsrc + w * 1024 + lane * 4;
        float* l = &WL[half][w * 1024];
        #pragma unroll
        for (int j = 0; j < 4; j++) {
            __builtin_amdgcn_global_load_lds(
                (const __attribute__((address_space(1))) unsigned int*)(g + j * 256),
                (__attribute__((address_space(3))) unsigned int*)(l + j * 256),
                16, 0, 0);
        }
    };

    stage_w(W_pxx, 0);                      // pre-A: phase B's weights

    // ---- phase A: issue W_dte; conv, Yb copy, residual+gelu ----
    stage_w(W_dte, 1);
    float4 rsv[2];
    #pragma unroll
    for (int i = 0; i < 2; i++) {
        int r = rg * 2 + i;
        // buf_y raw bf16 copy
        uint2 v = *(const uint2*)(buf_y + (size_t)(r0 + r) * 64 + cg * 4);
        *(uint2*)(&Ybh[r * 72 + cg * 4]) = v;
        // out residual -> registers; gelu -> GA
        rsv[i] = *(const float4*)(out + (size_t)(r0 + r) * 64 + cg * 4);
        GA[r * 68 + cg * 4 + 0] = gelu_f(rsv[i].x);
        GA[r * 68 + cg * 4 + 1] = gelu_f(rsv[i].y);
        GA[r * 68 + cg * 4 + 2] = gelu_f(rsv[i].z);
        GA[r * 68 + cg * 4 + 3] = gelu_f(rsv[i].w);
    }
    {   // depthwise 3x3 conv on t1, * gelu * t2 -> C0 (8 rows/wave)
        float c0 = conv_sh[lane * 9 + 0], c1 = conv_sh[lane * 9 + 1], c2 = conv_sh[lane * 9 + 2];
        float c3 = conv_sh[lane * 9 + 3], c4 = conv_sh[lane * 9 + 4], c5 = conv_sh[lane * 9 + 5];
        float c6 = conv_sh[lane * 9 + 6], c7 = conv_sh[lane * 9 + 7], c8 = conv_sh[lane * 9 + 8];
        #pragma unroll
        for (int i = 0; i < 8; i++) {
            int l = w * 8 + i;
            int gr = r0 + l;
            int pix = gr & 255, ii = pix >> 4, jj = pix & 15;
            const u16* p = t1 + (size_t)gr * 64 + lane;
            float c = c4 * bf2f(p[0]);
            if (ii > 0) {
                c += c1 * bf2f(p[-1024]);
                if (jj > 0)  c += c0 * bf2f(p[-1024 - 64]);
                if (jj < 15) c += c2 * bf2f(p[-1024 + 64]);
            }
            if (jj > 0)  c += c3 * bf2f(p[-64]);
            if (jj < 15) c += c5 * bf2f(p[64]);
            if (ii < 15) {
                c += c7 * bf2f(p[1024]);
                if (jj > 0)  c += c6 * bf2f(p[1024 - 64]);
                if (jj < 15) c += c8 * bf2f(p[1024 + 64]);
            }
            C0[l * 68 + lane] = gelu_f(c) * bf2f(t2[(size_t)gr * 64 + lane]);
        }
    }
    __syncthreads();    // drains vmcnt(0): W_pxx (and W_dte) landed

    // ---- phase B: SH1 = C0 @ W_pxx(WL0) + b_pxx + buf_sh ----
    {
        float acc[2][4] = {};
        const float* ur = C0 + rg * 2 * 68;
        #pragma unroll 8
        for (int kk = 0; kk < 64; kk++) {
            float a0 = ur[kk], a1 = ur[68 + kk];
            float4 wv = *(const float4*)(&WL[0][kk * 64 + cg * 4]);
            acc[0][0] += a0 * wv.x; acc[0][1] += a0 * wv.y; acc[0][2] += a0 * wv.z; acc[0][3] += a0 * wv.w;
            acc[1][0] += a1 * wv.x; acc[1][1] += a1 * wv.y; acc[1][2] += a1 * wv.z; acc[1][3] += a1 * wv.w;
        }
        float4 bp = *(const float4*)(b_pxx + cg * 4);
        #pragma unroll
        for (int i = 0; i < 2; i++) {
            int r = rg * 2 + i;
            float4 shv = *(const float4*)(buf_sh + (size_t)(r0 + r) * 64 + cg * 4);
            *(float4*)(SH1 + r * 68 + cg * 4) =
                make_float4(acc[i][0] + bp.x + shv.x, acc[i][1] + bp.y + shv.y,
                            acc[i][2] + bp.z + shv.z, acc[i][3] + bp.w + shv.w);
        }
    }
    __syncthreads();

    // ---- phase C1: issue W_dteall->WL0; accC = Yb @ W_dte(WL1) ----
    float accC[2][4] = {};
    stage_w(W_dteall, 0);
    {
        const u16* yr = Ybh + rg * 2 * 72;
        #pragma unroll 8
        for (int kk = 0; kk < 64; kk++) {
            float y0 = bf2f(yr[kk]), y1 = bf2f(yr[72 + kk]);
            float4 wv = *(const float4*)(&WL[1][kk * 64 + cg * 4]);
            accC[0][0] += y0 * wv.x; accC[0][1] += y0 * wv.y; accC[0][2] += y0 * wv.z; accC[0][3] += y0 * wv.w;
            accC[1][0] += y1 * wv.x; accC[1][1] += y1 * wv.y; accC[1][2] += y1 * wv.z; accC[1][3] += y1 * wv.w;
        }
    }
    __syncthreads();

    // ---- phase C2: issue W_fx->WL1; accC += SH1 @ W_dteall(WL0); GM = gelu ----
    stage_w(W_fx, 1);
    {
        const float* sr = SH1 + rg * 2 * 68;
        #pragma unroll 8
        for (int kk = 0; kk < 64; kk++) {
            float s0 = sr[kk], s1 = sr[68 + kk];
            float4 wv = *(const float4*)(&WL[0][kk * 64 + cg * 4]);
            accC[0][0] += s0 * wv.x; accC[0][1] += s0 * wv.y; accC[0][2] += s0 * wv.z; accC[0][3] += s0 * wv.w;
            accC[1][0] += s1 * wv.x; accC[1][1] += s1 * wv.y; accC[1][2] += s1 * wv.z; accC[1][3] += s1 * wv.w;
        }
        float4 bd1 = *(const float4*)(b_dte + cg * 4);
        float4 bd2 = *(const float4*)(b_dteall + cg * 4);
        #pragma unroll
        for (int i = 0; i < 2; i++) {
            int r = rg * 2 + i;
            *(float4*)(GM + r * 68 + cg * 4) =
                make_float4(gelu_f(accC[i][0] + bd1.x + bd2.x), gelu_f(accC[i][1] + bd1.y + bd2.y),
                            gelu_f(accC[i][2] + bd1.z + bd2.z), gelu_f(accC[i][3] + bd1.w + bd2.w));
        }
    }
    __syncthreads();

    // ---- phase D1: issue W_fmod->WL0; accA = GA @ W_fx(WL1) ----
    float accA[2][4] = {};
    stage_w(W_fmod, 0);
    {
        const float* ga = GA + rg * 2 * 68;
        #pragma unroll 8
        for (int kk = 0; kk < 64; kk++) {
            float a0 = ga[kk], a1 = ga[68 + kk];
            float4 wv = *(const float4*)(&WL[1][kk * 64 + cg * 4]);
            accA[0][0] += a0 * wv.x; accA[0][1] += a0 * wv.y; accA[0][2] += a0 * wv.z; accA[0][3] += a0 * wv.w;
            accA[1][0] += a1 * wv.x; accA[1][1] += a1 * wv.y; accA[1][2] += a1 * wv.z; accA[1][3] += a1 * wv.w;
        }
    }
    __syncthreads();

    // ---- phase D2: issue W_fxx->WL1; accM = GM @ W_fmod(WL0);
    //      P(C0) = gelu(accM+bm) * (accA+bx) ----
    stage_w(W_fxx, 1);
    {
        float accM[2][4] = {};
        const float* gm = GM + rg * 2 * 68;
        #pragma unroll 8
        for (int kk = 0; kk < 64; kk++) {
            float m0 = gm[kk], m1 = gm[68 + kk];
            float4 wv = *(const float4*)(&WL[0][kk * 64 + cg * 4]);
            accM[0][0] += m0 * wv.x; accM[0][1] += m0 * wv.y; accM[0][2] += m0 * wv.z; accM[0][3] += m0 * wv.w;
            accM[1][0] += m1 * wv.x; accM[1][1] += m1 * wv.y; accM[1][2] += m1 * wv.z; accM[1][3] += m1 * wv.w;
        }
        float4 bx = *(const float4*)(b_fx + cg * 4);
        float4 bm = *(const float4*)(b_fmod + cg * 4);
        #pragma unroll
        for (int i = 0; i < 2; i++) {
            int r = rg * 2 + i;
            float a0 = accA[i][0] + bx.x, a1 = accA[i][1] + bx.y, a2 = accA[i][2] + bx.z, a3 = accA[i][3] + bx.w;
            float m0 = accM[i][0] + bm.x, m1 = accM[i][1] + bm.y, m2 = accM[i][2] + bm.z, m3 = accM[i][3] + bm.w;
            *(float4*)(C0 + r * 68 + cg * 4) =
                make_float4(gelu_f(m0) * a0, gelu_f(m1) * a1, gelu_f(m2) * a2, gelu_f(m3) * a3);
        }
    }
    __syncthreads();

    // ---- phase E: out = P(C0) @ W_fxx(WL1) + b_fxx + rsv ----
    {
        float acc[2][4] = {};
        const float* pr = C0 + rg * 2 * 68;
        #pragma unroll 8
        for (int kk = 0; kk < 64; kk++) {
            float p0 = pr[kk], p1 = pr[68 + kk];
            float4 wv = *(const float4*)(&WL[1][kk * 64 + cg * 4]);
            acc[0][0] += p0 * wv.x; acc[0][1] += p0 * wv.y; acc[0][2] += p0 * wv.z; acc[0][3] += p0 * wv.w;
            acc[1][0] += p1 * wv.x; acc[1][1] += p1 * wv.y; acc[1][2] += p1 * wv.z; acc[1][3] += p1 * wv.w;
        }
        float4 bo = *(const float4*)(b_fxx + cg * 4);
        #pragma unroll
        for (int i = 0; i < 2; i++) {
            int r = rg * 2 + i;
            *(float4*)(out + (size_t)(r0 + r) * 64 + cg * 4) =
                make_float4(acc[i][0] + bo.x + rsv[i].x, acc[i][1] + bo.y + rsv[i].y,
                            acc[i][2] + bo.z + rsv[i].z, acc[i][3] + bo.w + rsv[i].w);
        }
    }
}

extern "C" void kernel_launch(void* const* d_in, const int* in_sizes, int n_in,
                              void* d_out, int out_size, void* d_ws, size_t ws_size,
                              hipStream_t stream) {
    const float* x       = (const float*)d_in[0];
    const float* dte     = (const float*)d_in[1];
    const float* w_gate  = (const float*)d_in[2];
    const float* W_exp   = (const float*)d_in[3];
    const float* b_exp   = (const float*)d_in[4];
    const float* W_sh    = (const float*)d_in[5];
    const float* b_sh    = (const float*)d_in[6];
    const float* ln_g    = (const float*)d_in[7];
    const float* ln_b    = (const float*)d_in[8];
    const float* W_px    = (const float*)d_in[9];
    const float* b_px    = (const float*)d_in[10];
    const float* conv_sh = (const float*)d_in[11];
    const float* W_pxx   = (const float*)d_in[12];
    const float* b_pxx   = (const float*)d_in[13];
    const float* W_dte   = (const float*)d_in[14];
    const float* b_dte   = (const float*)d_in[15];
    const float* W_dteall= (const float*)d_in[16];
    const float* b_dteall= (const float*)d_in[17];
    const float* W_rgb   = (const float*)d_in[18];
    const float* b_rgb   = (const float*)d_in[19];
    const float* W_fx    = (const float*)d_in[20];
    const float* b_fx    = (const float*)d_in[21];
    const float* W_fmod  = (const float*)d_in[22];
    const float* b_fmod  = (const float*)d_in[23];
    const float* W_fxx   = (const float*)d_in[24];
    const float* b_fxx   = (const float*)d_in[25];

    float* out = (float*)d_out;     // [0,1048576) plane + loss at [1048576]

    float* wsf    = (float*)d_ws;
    float* partial= wsf;                         // 2048
    int*   topi   = (int*)(wsf + 2048);          // 128
    float* topg   = wsf + 2176;                  // 128
    float* bias_y = wsf + 2304;                  // 4096
    float* buf_sh = wsf + 8192;                  // 1048576 f32
    u16*   buf_y  = (u16*)(wsf + 8192 + 1048576);
    u16*   t1     = (u16*)(wsf + 8192 + 1048576 + 524288);
    u16*   t2     = (u16*)(wsf + 8192 + 1048576 + 524288*2);

    hipLaunchKernelGGL(k_gate_part, dim3(256), dim3(256), 0, stream, dte, w_gate, partial);
    hipLaunchKernelGGL(k_gate_fin, dim3(1), dim3(256), 0, stream,
                       partial, b_exp, topi, topg, bias_y, out + 1048576);
    hipLaunchKernelGGL(k_gemm3, dim3(512), dim3(256), 0, stream,
                       dte, x, W_sh, b_sh, W_exp, topi, topg, bias_y, W_rgb, b_rgb,
                       buf_sh, buf_y, out);
    hipLaunchKernelGGL(k_lnpx, dim3(512), dim3(256), 0, stream,
                       buf_sh, ln_g, ln_b, W_px, b_px, t1, t2);
    hipLaunchKernelGGL(k_tail, dim3(512), dim3(256), 0, stream,
                       t1, t2, conv_sh, W_pxx, b_pxx, buf_sh, buf_y,
                       W_dte, b_dte, W_dteall, b_dteall,
                       W_fx, b_fx, W_fmod, b_fmod, W_fxx, b_fxx, out);

    (void)in_sizes; (void)n_in; (void)out_size; (void)ws_size;
}